// Round 1
// baseline (4163.531 us; speedup 1.0000x reference)
//
#include <hip/hip_runtime.h>
#include <hip/hip_bf16.h>
#include <math.h>

// Problem constants
#define B_  2
#define T_  2048
#define C_  1536
#define H_  12
#define KV_ 4
#define D_  128
#define M_  (B_*T_)   // 4096 rows

// ---------------------------------------------------------------------------
// GEMM: C[M,N] = A[M,K] * B[N,K]^T   (all row-major, fp32)
// 64x64 tile, BK=16, 256 threads, 4x4 microtile per thread.
// M,N multiples of 64; K multiple of 16 (true for all our shapes).
// ---------------------------------------------------------------------------
__global__ __launch_bounds__(256) void gemm_bt(const float* __restrict__ A,
                                               const float* __restrict__ Bm,
                                               float* __restrict__ C,
                                               int M, int N, int K) {
    __shared__ float As[16][65];
    __shared__ float Bs[16][65];
    const int tid = threadIdx.x;
    const int bm = blockIdx.y * 64;
    const int bn = blockIdx.x * 64;
    const int lr = tid >> 2;          // 0..63 (row within tile for loads)
    const int lk = (tid & 3) * 4;     // 0,4,8,12 (k within tile for loads)
    const int tm = (tid >> 4) * 4;    // 0..60
    const int tn = (tid & 15) * 4;    // 0..60
    float acc[4][4] = {};
    for (int k0 = 0; k0 < K; k0 += 16) {
        float4 av = *(const float4*)&A [(size_t)(bm + lr) * K + k0 + lk];
        float4 bv = *(const float4*)&Bm[(size_t)(bn + lr) * K + k0 + lk];
        As[lk+0][lr] = av.x; As[lk+1][lr] = av.y; As[lk+2][lr] = av.z; As[lk+3][lr] = av.w;
        Bs[lk+0][lr] = bv.x; Bs[lk+1][lr] = bv.y; Bs[lk+2][lr] = bv.z; Bs[lk+3][lr] = bv.w;
        __syncthreads();
        #pragma unroll
        for (int kk = 0; kk < 16; kk++) {
            float a0 = As[kk][tm+0], a1 = As[kk][tm+1], a2 = As[kk][tm+2], a3 = As[kk][tm+3];
            float b0 = Bs[kk][tn+0], b1 = Bs[kk][tn+1], b2 = Bs[kk][tn+2], b3 = Bs[kk][tn+3];
            acc[0][0] += a0*b0; acc[0][1] += a0*b1; acc[0][2] += a0*b2; acc[0][3] += a0*b3;
            acc[1][0] += a1*b0; acc[1][1] += a1*b1; acc[1][2] += a1*b2; acc[1][3] += a1*b3;
            acc[2][0] += a2*b0; acc[2][1] += a2*b1; acc[2][2] += a2*b2; acc[2][3] += a2*b3;
            acc[3][0] += a3*b0; acc[3][1] += a3*b1; acc[3][2] += a3*b2; acc[3][3] += a3*b3;
        }
        __syncthreads();
    }
    #pragma unroll
    for (int i = 0; i < 4; i++)
        #pragma unroll
        for (int j = 0; j < 4; j++)
            C[(size_t)(bm + tm + i) * N + bn + tn + j] = acc[i][j];
}

// ---------------------------------------------------------------------------
// v[b,t,g,:] += 3*sigmoid(x[b,t,:12] . Wg[g,:]) * ve[b,t,g,:]
// grid: (B*T)*KV blocks, 128 threads (one per d)
// ---------------------------------------------------------------------------
__global__ __launch_bounds__(128) void gate_ve(float* __restrict__ v,
                                               const float* __restrict__ x,
                                               const float* __restrict__ ve,
                                               const float* __restrict__ Wg) {
    const int idx = blockIdx.x;       // (b*T+t)*KV + g
    const int g = idx & 3;
    const int bt = idx >> 2;
    const int d = threadIdx.x;
    float acc = 0.f;
    const float* xr = x + (size_t)bt * C_;
    #pragma unroll
    for (int c = 0; c < 12; c++) acc += xr[c] * Wg[g * 12 + c];
    const float gate = 3.0f / (1.0f + expf(-acc));
    const size_t o = (size_t)idx * D_ + d;
    v[o] += gate * ve[o];
}

// ---------------------------------------------------------------------------
// In-place RoPE + RMSNorm*1.2 on q or k. One wave per (b,t,h).
// p layout: [(b*T+t)*nh + h][128]; cos/sin: [t][64]
// ---------------------------------------------------------------------------
__global__ __launch_bounds__(64) void rope_rms(float* __restrict__ qk,
                                               const float* __restrict__ cosb,
                                               const float* __restrict__ sinb,
                                               int nh) {
    const int idx = blockIdx.x;       // (b*T+t)*nh + h
    const int bt = idx / nh;
    const int t = bt & (T_ - 1);
    float* p = qk + (size_t)idx * D_;
    const int i = threadIdx.x;        // 0..63
    const float x1 = p[i], x2 = p[i + 64];
    const float c = cosb[t * 64 + i], s = sinb[t * 64 + i];
    const float o1 =  x1 * c + x2 * s;
    const float o2 = -x1 * s + x2 * c;
    float ss = o1 * o1 + o2 * o2;
    #pragma unroll
    for (int off = 32; off > 0; off >>= 1) ss += __shfl_down(ss, off);
    ss = __shfl(ss, 0);
    const float scale = rsqrtf(ss * (1.0f / 128.0f) + 1.1920928955078125e-07f) * 1.2f;
    p[i]      = o1 * scale;
    p[i + 64] = o2 * scale;
}

// ---------------------------------------------------------------------------
// Attention, one block (128 threads) per (b,h,t) query row.
// q,y: [(b*T+t)*H + h][128]; k,v: [(b*T+s)*KV + g][128]
// ---------------------------------------------------------------------------
__global__ __launch_bounds__(128) void attn(const float* __restrict__ q,
                                            const float* __restrict__ k,
                                            const float* __restrict__ v,
                                            float* __restrict__ y,
                                            const int* __restrict__ wptr) {
    const int t = blockIdx.x, h = blockIdx.y, b = blockIdx.z;
    const int g = h / (H_ / KV_);
    const int tid = threadIdx.x;
    __shared__ float qs[D_];
    __shared__ float sc[T_];
    __shared__ float red[4];

    const int w = *wptr;
    int s0 = 0;
    if (w >= 0 && w < T_) { s0 = t - w; if (s0 < 0) s0 = 0; }
    const int ns = t - s0 + 1;

    qs[tid] = q[((size_t)(b * T_ + t) * H_ + h) * D_ + tid];
    __syncthreads();

    // scores
    for (int si = tid; si < ns; si += 128) {
        const float* kp = k + ((size_t)(b * T_ + s0 + si) * KV_ + g) * D_;
        float acc = 0.f;
        #pragma unroll 8
        for (int d = 0; d < D_; d++) acc += qs[d] * kp[d];
        sc[si] = acc * 0.08838834764831845f;   // 1/sqrt(128)
    }
    __syncthreads();

    // max
    float m = -INFINITY;
    for (int si = tid; si < ns; si += 128) m = fmaxf(m, sc[si]);
    #pragma unroll
    for (int off = 32; off > 0; off >>= 1) m = fmaxf(m, __shfl_down(m, off));
    if ((tid & 63) == 0) red[tid >> 6] = m;
    __syncthreads();
    m = fmaxf(red[0], red[1]);

    // exp + sum
    float ssum = 0.f;
    for (int si = tid; si < ns; si += 128) {
        float e = __expf(sc[si] - m);
        sc[si] = e;
        ssum += e;
    }
    #pragma unroll
    for (int off = 32; off > 0; off >>= 1) ssum += __shfl_down(ssum, off);
    if ((tid & 63) == 0) red[2 + (tid >> 6)] = ssum;
    __syncthreads();
    const float denom = red[2] + red[3];

    // y_d = sum_s p_s * v[s,d]
    float acc = 0.f;
    const float* vp = v + ((size_t)(b * T_ + s0) * KV_ + g) * D_ + tid;
    for (int si = 0; si < ns; si++) acc += sc[si] * vp[(size_t)si * KV_ * D_];
    y[((size_t)(b * T_ + t) * H_ + h) * D_ + tid] = acc / denom;
}

// ---------------------------------------------------------------------------
extern "C" void kernel_launch(void* const* d_in, const int* in_sizes, int n_in,
                              void* d_out, int out_size, void* d_ws, size_t ws_size,
                              hipStream_t stream) {
    const float* x     = (const float*)d_in[0];
    const float* ve    = (const float*)d_in[1];
    const float* cosb  = (const float*)d_in[2];
    const float* sinb  = (const float*)d_in[3];
    const float* Wq    = (const float*)d_in[4];
    const float* Wk    = (const float*)d_in[5];
    const float* Wv    = (const float*)d_in[6];
    const float* Wproj = (const float*)d_in[7];
    const float* Wg    = (const float*)d_in[8];
    const int*   wptr  = (const int*)d_in[9];
    float* out = (float*)d_out;
    float* ws  = (float*)d_ws;

    float* q = ws;                         // 4096*1536
    float* k = ws + (size_t)M_ * C_;       // 4096*512
    float* v = k + (size_t)M_ * KV_ * D_;  // 4096*512
    float* y = v + (size_t)M_ * KV_ * D_;  // 4096*1536

    // q = x @ Wq^T ; k = x @ Wk^T ; v = x @ Wv^T
    gemm_bt<<<dim3(C_ / 64, M_ / 64), 256, 0, stream>>>(x, Wq, q, M_, C_, C_);
    gemm_bt<<<dim3((KV_ * D_) / 64, M_ / 64), 256, 0, stream>>>(x, Wk, k, M_, KV_ * D_, C_);
    gemm_bt<<<dim3((KV_ * D_) / 64, M_ / 64), 256, 0, stream>>>(x, Wv, v, M_, KV_ * D_, C_);

    // v += gate * ve
    gate_ve<<<M_ * KV_, 128, 0, stream>>>(v, x, ve, Wg);

    // rope + rmsnorm
    rope_rms<<<M_ * H_, 64, 0, stream>>>(q, cosb, sinb, H_);
    rope_rms<<<M_ * KV_, 64, 0, stream>>>(k, cosb, sinb, KV_);

    // attention
    attn<<<dim3(T_, H_, B_), 128, 0, stream>>>(q, k, v, y, wptr);

    // out = y @ Wproj^T
    gemm_bt<<<dim3(C_ / 64, M_ / 64), 256, 0, stream>>>(y, Wproj, out, M_, C_, C_);
}

// Round 2
// 1380.173 us; speedup vs baseline: 3.0167x; 3.0167x over previous
//
#include <hip/hip_runtime.h>
#include <hip/hip_bf16.h>
#include <math.h>

// Problem constants
#define B_  2
#define T_  2048
#define C_  1536
#define H_  12
#define KV_ 4
#define D_  128
#define M_  (B_*T_)   // 4096 rows
#define REP_ (H_/KV_) // 3

typedef __bf16 bf16x8 __attribute__((ext_vector_type(8)));
typedef float  f32x4  __attribute__((ext_vector_type(4)));
typedef unsigned u32x4 __attribute__((ext_vector_type(4)));

union BCast { u32x4 u; bf16x8 b; };

__device__ inline bf16x8 ldb8(const ushort* p) {
    BCast c; c.u = *reinterpret_cast<const u32x4*>(p); return c.b;
}

__device__ inline ushort f2bf(float f) {
    union { float f; unsigned u; } v; v.f = f;
    unsigned u = v.u;
    return (ushort)((u + 0x7FFF + ((u >> 16) & 1)) >> 16);
}

// ---------------------------------------------------------------------------
// GEMM: C[M,N] = A[M,K] * B[N,K]^T   (row-major fp32) — unchanged from R1
// ---------------------------------------------------------------------------
__global__ __launch_bounds__(256) void gemm_bt(const float* __restrict__ A,
                                               const float* __restrict__ Bm,
                                               float* __restrict__ C,
                                               int M, int N, int K) {
    __shared__ float As[16][65];
    __shared__ float Bs[16][65];
    const int tid = threadIdx.x;
    const int bm = blockIdx.y * 64;
    const int bn = blockIdx.x * 64;
    const int lr = tid >> 2;
    const int lk = (tid & 3) * 4;
    const int tm = (tid >> 4) * 4;
    const int tn = (tid & 15) * 4;
    float acc[4][4] = {};
    for (int k0 = 0; k0 < K; k0 += 16) {
        float4 av = *(const float4*)&A [(size_t)(bm + lr) * K + k0 + lk];
        float4 bv = *(const float4*)&Bm[(size_t)(bn + lr) * K + k0 + lk];
        As[lk+0][lr] = av.x; As[lk+1][lr] = av.y; As[lk+2][lr] = av.z; As[lk+3][lr] = av.w;
        Bs[lk+0][lr] = bv.x; Bs[lk+1][lr] = bv.y; Bs[lk+2][lr] = bv.z; Bs[lk+3][lr] = bv.w;
        __syncthreads();
        #pragma unroll
        for (int kk = 0; kk < 16; kk++) {
            float a0 = As[kk][tm+0], a1 = As[kk][tm+1], a2 = As[kk][tm+2], a3 = As[kk][tm+3];
            float b0 = Bs[kk][tn+0], b1 = Bs[kk][tn+1], b2 = Bs[kk][tn+2], b3 = Bs[kk][tn+3];
            acc[0][0] += a0*b0; acc[0][1] += a0*b1; acc[0][2] += a0*b2; acc[0][3] += a0*b3;
            acc[1][0] += a1*b0; acc[1][1] += a1*b1; acc[1][2] += a1*b2; acc[1][3] += a1*b3;
            acc[2][0] += a2*b0; acc[2][1] += a2*b1; acc[2][2] += a2*b2; acc[2][3] += a2*b3;
            acc[3][0] += a3*b0; acc[3][1] += a3*b1; acc[3][2] += a3*b2; acc[3][3] += a3*b3;
        }
        __syncthreads();
    }
    #pragma unroll
    for (int i = 0; i < 4; i++)
        #pragma unroll
        for (int j = 0; j < 4; j++)
            C[(size_t)(bm + tm + i) * N + bn + tn + j] = acc[i][j];
}

// ---------------------------------------------------------------------------
// RoPE + RMSNorm, fp32 in [(b*T+t)*nh + h][128] -> bf16 out [((b*nh+h)*T + t)][128]
// outscale folds the 1.2*1.2/sqrt(D) attention scaling (for Q; 1.0 for K).
// ---------------------------------------------------------------------------
__global__ __launch_bounds__(64) void rope_rms_cast(const float* __restrict__ qk,
                                                    ushort* __restrict__ outp,
                                                    const float* __restrict__ cosb,
                                                    const float* __restrict__ sinb,
                                                    int nh, float outscale) {
    const int idx = blockIdx.x;       // (b*T+t)*nh + h
    const int bt = idx / nh;
    const int h  = idx - bt * nh;
    const int b  = bt >> 11;          // T_ = 2048
    const int t  = bt & (T_ - 1);
    const float* p = qk + (size_t)idx * D_;
    const int i = threadIdx.x;        // 0..63
    const float x1 = p[i], x2 = p[i + 64];
    const float c = cosb[t * 64 + i], s = sinb[t * 64 + i];
    const float o1 =  x1 * c + x2 * s;
    const float o2 = -x1 * s + x2 * c;
    float ss = o1 * o1 + o2 * o2;
    #pragma unroll
    for (int off = 32; off > 0; off >>= 1) ss += __shfl_down(ss, off);
    ss = __shfl(ss, 0);
    const float scale = rsqrtf(ss * (1.0f / 128.0f) + 1.1920928955078125e-07f) * outscale;
    ushort* op = outp + ((size_t)(b * nh + h) * T_ + t) * D_;
    op[i]      = f2bf(o1 * scale);
    op[i + 64] = f2bf(o2 * scale);
}

// ---------------------------------------------------------------------------
// Fused ve-gate + transpose: Vt[b][g][d][s] bf16 = v[b][s][g][d] + gate*ve
// Block: 64 t-rows x all 128 d for one (b,g). grid (T/64, KV, B), 256 thr.
// ---------------------------------------------------------------------------
__global__ __launch_bounds__(256) void gate_vt(const float* __restrict__ v,
                                               const float* __restrict__ x,
                                               const float* __restrict__ ve,
                                               const float* __restrict__ Wg,
                                               ushort* __restrict__ Vt) {
    const int t0 = blockIdx.x * 64, g = blockIdx.y, b = blockIdx.z;
    __shared__ float gateS[64];
    __shared__ ushort tile[128][66];   // [d][t], padded
    const int tid = threadIdx.x;
    if (tid < 64) {
        const float* xr = x + (size_t)(b * T_ + t0 + tid) * C_;
        float acc = 0.f;
        #pragma unroll
        for (int c = 0; c < 12; c++) acc += xr[c] * Wg[g * 12 + c];
        gateS[tid] = 3.0f / (1.0f + __expf(-acc));
    }
    __syncthreads();
    #pragma unroll
    for (int i = 0; i < 32; i++) {
        int idx = i * 256 + tid;       // 0..8191
        int r = idx >> 7;              // t within tile
        int d = idx & 127;
        size_t off = ((size_t)(b * T_ + t0 + r) * KV_ + g) * D_ + d;
        tile[d][r] = f2bf(v[off] + gateS[r] * ve[off]);
    }
    __syncthreads();
    ushort* ob = Vt + ((size_t)(b * KV_ + g) * D_) * T_ + t0;
    #pragma unroll
    for (int i = 0; i < 32; i++) {
        int idx = i * 256 + tid;
        int d = idx >> 6;              // 0..127
        int c = idx & 63;
        ob[(size_t)d * T_ + c] = tile[d][c];
    }
}

// ---------------------------------------------------------------------------
// Flash attention, 1 wave per (b, h, 16-query tile). mfma 16x16x32 bf16.
// Qp[b][h][t][d] (pre-scaled), Kp[b][g][s][d], Vt[b][g][d][s]; y fp32 [b][t][h*D]
// ---------------------------------------------------------------------------
__global__ __launch_bounds__(64) void attn_mfma(const ushort* __restrict__ Qp,
                                                const ushort* __restrict__ Kp,
                                                const ushort* __restrict__ Vt,
                                                float* __restrict__ y,
                                                const int* __restrict__ wptr) {
    const int t0 = blockIdx.x * 16;
    const int h  = blockIdx.y, b = blockIdx.z;
    const int g  = h / REP_;
    const int lane = threadIdx.x;
    const int m16 = lane & 15, quad = lane >> 4;
    __shared__ ushort Pl[16 * 40];     // P transform buffer, row stride 40 (80B, 16B-mult)

    const int w = *wptr;
    const bool windowed = (w >= 0 && w < T_);
    int s_lo = 0;
    if (windowed) { s_lo = t0 - w; if (s_lo < 0) s_lo = 0; }
    const int s_hi = t0 + 15;
    const int ss0 = s_lo & ~31;

    // A-frags of Q: A[m=lane&15][k=quad*8+j], 4 chunks of K=32 over D=128
    const ushort* qrow = Qp + ((size_t)(b * H_ + h) * T_ + t0 + m16) * D_ + quad * 8;
    bf16x8 qa[4];
    #pragma unroll
    for (int kc = 0; kc < 4; kc++) qa[kc] = ldb8(qrow + kc * 32);

    const ushort* kbase = Kp + (size_t)(b * KV_ + g) * T_ * D_;
    const ushort* vbase = Vt + (size_t)(b * KV_ + g) * D_ * T_;

    f32x4 o[8];
    #pragma unroll
    for (int dt = 0; dt < 8; dt++) o[dt] = (f32x4){0.f, 0.f, 0.f, 0.f};
    float mrow[4] = {-1e30f, -1e30f, -1e30f, -1e30f};
    float lrow[4] = {0.f, 0.f, 0.f, 0.f};

    for (int ss = ss0; ss <= s_hi; ss += 32) {
        // ---- S = Q K^T (16 x 32) ----
        f32x4 s0 = (f32x4){0.f,0.f,0.f,0.f};
        f32x4 s1 = (f32x4){0.f,0.f,0.f,0.f};
        const ushort* k0r = kbase + (size_t)(ss      + m16) * D_ + quad * 8;
        const ushort* k1r = kbase + (size_t)(ss + 16 + m16) * D_ + quad * 8;
        #pragma unroll
        for (int kc = 0; kc < 4; kc++) {
            bf16x8 kf0 = ldb8(k0r + kc * 32);
            bf16x8 kf1 = ldb8(k1r + kc * 32);
            s0 = __builtin_amdgcn_mfma_f32_16x16x32_bf16(qa[kc], kf0, s0, 0, 0, 0);
            s1 = __builtin_amdgcn_mfma_f32_16x16x32_bf16(qa[kc], kf1, s1, 0, 0, 0);
        }

        // ---- mask + online softmax (C layout: col=lane&15, row=quad*4+reg) ----
        const int sA = ss + m16, sB = ss + 16 + m16;
        #pragma unroll
        for (int reg = 0; reg < 4; reg++) {
            const int t = t0 + quad * 4 + reg;
            const bool vA = (sA <= t) && (!windowed || (t - sA) <= w);
            const bool vB = (sB <= t) && (!windowed || (t - sB) <= w);
            float a  = vA ? s0[reg] : -1e30f;
            float bb = vB ? s1[reg] : -1e30f;
            float mt = fmaxf(a, bb);
            mt = fmaxf(mt, __shfl_xor(mt, 1));
            mt = fmaxf(mt, __shfl_xor(mt, 2));
            mt = fmaxf(mt, __shfl_xor(mt, 4));
            mt = fmaxf(mt, __shfl_xor(mt, 8));
            const float mnew  = fmaxf(mrow[reg], mt);
            const float alpha = __expf(mrow[reg] - mnew);
            mrow[reg] = mnew;
            const float pa = vA ? __expf(s0[reg] - mnew) : 0.f;
            const float pb = vB ? __expf(s1[reg] - mnew) : 0.f;
            float rs = pa + pb;
            rs += __shfl_xor(rs, 1);
            rs += __shfl_xor(rs, 2);
            rs += __shfl_xor(rs, 4);
            rs += __shfl_xor(rs, 8);
            lrow[reg] = lrow[reg] * alpha + rs;
            #pragma unroll
            for (int dt = 0; dt < 8; dt++) o[dt][reg] *= alpha;
            Pl[(quad * 4 + reg) * 40 + m16]      = f2bf(pa);
            Pl[(quad * 4 + reg) * 40 + 16 + m16] = f2bf(pb);
        }

        // ---- C-layout -> A-layout for P via LDS ----
        __syncthreads();
        bf16x8 pfrag = ldb8(&Pl[m16 * 40 + quad * 8]);
        __syncthreads();

        // ---- O += P V (V B-frag: B[k=quad*8+j][n=lane&15] = Vt[d][s] rows) ----
        const ushort* vcol = vbase + (size_t)m16 * T_ + ss + quad * 8;
        #pragma unroll
        for (int dt = 0; dt < 8; dt++) {
            bf16x8 vf = ldb8(vcol + (size_t)(dt * 16) * T_);
            o[dt] = __builtin_amdgcn_mfma_f32_16x16x32_bf16(pfrag, vf, o[dt], 0, 0, 0);
        }
    }

    // ---- epilogue: y[b][t][h*128 + d] = O / l ----
    float inv[4];
    #pragma unroll
    for (int reg = 0; reg < 4; reg++) inv[reg] = 1.0f / lrow[reg];
    float* yb = y + ((size_t)(b * T_ + t0 + quad * 4) * H_ + h) * D_ + m16;
    #pragma unroll
    for (int reg = 0; reg < 4; reg++)
        #pragma unroll
        for (int dt = 0; dt < 8; dt++)
            yb[(size_t)reg * H_ * D_ + dt * 16] = o[dt][reg] * inv[reg];
}

// ---------------------------------------------------------------------------
extern "C" void kernel_launch(void* const* d_in, const int* in_sizes, int n_in,
                              void* d_out, int out_size, void* d_ws, size_t ws_size,
                              hipStream_t stream) {
    const float* x     = (const float*)d_in[0];
    const float* ve    = (const float*)d_in[1];
    const float* cosb  = (const float*)d_in[2];
    const float* sinb  = (const float*)d_in[3];
    const float* Wq    = (const float*)d_in[4];
    const float* Wk    = (const float*)d_in[5];
    const float* Wv    = (const float*)d_in[6];
    const float* Wproj = (const float*)d_in[7];
    const float* Wg    = (const float*)d_in[8];
    const int*   wptr  = (const int*)d_in[9];
    float* out = (float*)d_out;
    float* ws  = (float*)d_ws;

    float* q  = ws;                               // M*C fp32 (reused as y)
    float* k  = q + (size_t)M_ * C_;              // M*512 fp32
    float* v  = k + (size_t)M_ * KV_ * D_;        // M*512 fp32
    ushort* Qp = (ushort*)(v + (size_t)M_ * KV_ * D_);  // M*1536 bf16
    ushort* Kp = Qp + (size_t)M_ * H_ * D_;             // M*512 bf16
    ushort* Vt = Kp + (size_t)M_ * KV_ * D_;            // M*512 bf16 (transposed)

    // projections (fp32)
    gemm_bt<<<dim3(C_ / 64, M_ / 64), 256, 0, stream>>>(x, Wq, q, M_, C_, C_);
    gemm_bt<<<dim3((KV_ * D_) / 64, M_ / 64), 256, 0, stream>>>(x, Wk, k, M_, KV_ * D_, C_);
    gemm_bt<<<dim3((KV_ * D_) / 64, M_ / 64), 256, 0, stream>>>(x, Wv, v, M_, KV_ * D_, C_);

    // ve-gate + transpose -> Vt bf16
    gate_vt<<<dim3(T_ / 64, KV_, B_), 256, 0, stream>>>(v, x, ve, Wg, Vt);

    // rope + rmsnorm -> packed bf16 (Q carries 1.2*1.2/sqrt(D))
    rope_rms_cast<<<M_ * H_, 64, 0, stream>>>(q, Qp, cosb, sinb, H_,
                                              1.2f * 1.2f * 0.08838834764831845f);
    rope_rms_cast<<<M_ * KV_, 64, 0, stream>>>(k, Kp, cosb, sinb, KV_, 1.0f);

    // flash attention (writes y into q buffer, fp32)
    attn_mfma<<<dim3(T_ / 16, H_, B_), 64, 0, stream>>>(Qp, Kp, Vt, q, wptr);

    // out = y @ Wproj^T (fp32)
    gemm_bt<<<dim3(C_ / 64, M_ / 64), 256, 0, stream>>>(q, Wproj, out, M_, C_, C_);
}

// Round 3
// 455.727 us; speedup vs baseline: 9.1360x; 3.0285x over previous
//
#include <hip/hip_runtime.h>
#include <hip/hip_bf16.h>
#include <math.h>

// Problem constants
#define B_  2
#define T_  2048
#define C_  1536
#define H_  12
#define KV_ 4
#define D_  128
#define M_  (B_*T_)   // 4096 rows
#define REP_ (H_/KV_) // 3

typedef __bf16 bf16x8 __attribute__((ext_vector_type(8)));
typedef float  f32x4  __attribute__((ext_vector_type(4)));
typedef unsigned u32x4 __attribute__((ext_vector_type(4)));

union BCast { u32x4 u; bf16x8 b; };

__device__ inline bf16x8 ldb8(const ushort* p) {
    BCast c; c.u = *reinterpret_cast<const u32x4*>(p); return c.b;
}

__device__ inline ushort f2bf(float f) {
    union { float f; unsigned u; } v; v.f = f;
    unsigned u = v.u;
    return (ushort)((u + 0x7FFF + ((u >> 16) & 1)) >> 16);
}

__device__ inline float bf2f(ushort u) {
    union { unsigned u; float f; } v; v.u = (unsigned)u << 16;
    return v.f;
}

// async global->LDS, 16 bytes per lane; lds base must be wave-uniform
__device__ inline void async_copy16(const ushort* g, ushort* l) {
    __builtin_amdgcn_global_load_lds(
        (const __attribute__((address_space(1))) unsigned*)g,
        (__attribute__((address_space(3))) unsigned*)l, 16, 0, 0);
}

// ---------------------------------------------------------------------------
// bf16 MFMA GEMM (m97 structure): C[M,N] = A[M,K] * B[N,K]^T
// A,B bf16 row-major; C fp32 or bf16. 128x128 tile, BK=32, 256 thr / 4 waves,
// each wave 64x64 via 4x4 mfma_f32_16x16x32_bf16 accumulators.
// M,N % 128 == 0, K % 32 == 0.
// ---------------------------------------------------------------------------
template<bool BF16OUT>
__global__ __launch_bounds__(256) void gemm_bf16_bt(const ushort* __restrict__ A,
                                                    const ushort* __restrict__ Bm,
                                                    void* __restrict__ Cp,
                                                    int M, int N, int K) {
    __shared__ ushort As[128 * 32];
    __shared__ ushort Bs[128 * 32];
    const int tid  = threadIdx.x;
    const int wave = tid >> 6, lane = tid & 63;
    const int m16 = lane & 15, quad = lane >> 4;
    const int bm = blockIdx.y * 128, bn = blockIdx.x * 128;
    const int wm = (wave >> 1) * 64, wn = (wave & 1) * 64;

    // staging: per round, wave w covers 16 rows (64 lanes x 16B = 1KB)
    const int lrow = lane >> 2;        // 0..15
    const int lcol = (lane & 3) * 8;   // 0,8,16,24
    const ushort* Ag = A  + (size_t)(bm + wave * 16 + lrow) * K + lcol;
    const ushort* Bg = Bm + (size_t)(bn + wave * 16 + lrow) * K + lcol;
    ushort* AsW0 = As + wave * 512;          // rows wave*16..+15
    ushort* AsW1 = As + 2048 + wave * 512;   // rows 64+wave*16..+15
    ushort* BsW0 = Bs + wave * 512;
    ushort* BsW1 = Bs + 2048 + wave * 512;
    const size_t rowskip = (size_t)64 * K;

    f32x4 acc[4][4];
    #pragma unroll
    for (int i = 0; i < 4; i++)
        #pragma unroll
        for (int j = 0; j < 4; j++) acc[i][j] = (f32x4){0.f, 0.f, 0.f, 0.f};

    for (int k0 = 0; k0 < K; k0 += 32) {
        async_copy16(Ag + k0,           AsW0);
        async_copy16(Ag + k0 + rowskip, AsW1);
        async_copy16(Bg + k0,           BsW0);
        async_copy16(Bg + k0 + rowskip, BsW1);
        __syncthreads();

        bf16x8 af[4], bfr[4];
        #pragma unroll
        for (int i = 0; i < 4; i++)
            af[i] = ldb8(As + (wm + i * 16 + m16) * 32 + quad * 8);
        #pragma unroll
        for (int j = 0; j < 4; j++)
            bfr[j] = ldb8(Bs + (wn + j * 16 + m16) * 32 + quad * 8);
        #pragma unroll
        for (int i = 0; i < 4; i++)
            #pragma unroll
            for (int j = 0; j < 4; j++)
                acc[i][j] = __builtin_amdgcn_mfma_f32_16x16x32_bf16(af[i], bfr[j], acc[i][j], 0, 0, 0);
        __syncthreads();
    }

    // epilogue: C layout col=lane&15, row=quad*4+reg
    #pragma unroll
    for (int i = 0; i < 4; i++) {
        #pragma unroll
        for (int reg = 0; reg < 4; reg++) {
            const int row = bm + wm + i * 16 + quad * 4 + reg;
            if constexpr (BF16OUT) {
                ushort* C = (ushort*)Cp;
                #pragma unroll
                for (int j = 0; j < 4; j++)
                    C[(size_t)row * N + bn + wn + j * 16 + m16] = f2bf(acc[i][j][reg]);
            } else {
                float* C = (float*)Cp;
                #pragma unroll
                for (int j = 0; j < 4; j++)
                    C[(size_t)row * N + bn + wn + j * 16 + m16] = acc[i][j][reg];
            }
        }
    }
}

// ---------------------------------------------------------------------------
// fp32 -> bf16 cast, 4 elements/thread
// ---------------------------------------------------------------------------
__global__ __launch_bounds__(256) void cast_bf16(const float* __restrict__ in,
                                                 ushort* __restrict__ out, int n4) {
    int i = blockIdx.x * 256 + threadIdx.x;
    if (i < n4) {
        float4 v = ((const float4*)in)[i];
        ushort4 o = make_ushort4(f2bf(v.x), f2bf(v.y), f2bf(v.z), f2bf(v.w));
        ((ushort4*)out)[i] = o;
    }
}

// ---------------------------------------------------------------------------
// RoPE + RMSNorm, bf16 in [bt*rowstride + h*128] -> bf16 out [((b*nh+h)*T+t)*128]
// outscale folds 1.2*1.2/sqrt(D) for Q (1.0 for K).
// ---------------------------------------------------------------------------
__global__ __launch_bounds__(64) void rope_rms_cast(const ushort* __restrict__ qk,
                                                    ushort* __restrict__ outp,
                                                    const float* __restrict__ cosb,
                                                    const float* __restrict__ sinb,
                                                    int nh, int rowstride, float outscale) {
    const int idx = blockIdx.x;       // (b*T+t)*nh + h
    const int bt = idx / nh;
    const int h  = idx - bt * nh;
    const int b  = bt >> 11;          // T_ = 2048
    const int t  = bt & (T_ - 1);
    const ushort* p = qk + (size_t)bt * rowstride + h * D_;
    const int i = threadIdx.x;        // 0..63
    const float x1 = bf2f(p[i]), x2 = bf2f(p[i + 64]);
    const float c = cosb[t * 64 + i], s = sinb[t * 64 + i];
    const float o1 =  x1 * c + x2 * s;
    const float o2 = -x1 * s + x2 * c;
    float ss = o1 * o1 + o2 * o2;
    #pragma unroll
    for (int off = 32; off > 0; off >>= 1) ss += __shfl_down(ss, off);
    ss = __shfl(ss, 0);
    const float scale = rsqrtf(ss * (1.0f / 128.0f) + 1.1920928955078125e-07f) * outscale;
    ushort* op = outp + ((size_t)(b * nh + h) * T_ + t) * D_;
    op[i]      = f2bf(o1 * scale);
    op[i + 64] = f2bf(o2 * scale);
}

// ---------------------------------------------------------------------------
// Fused ve-gate + transpose: Vt[b][g][d][s] = v[bt][g*128+d] + gate*ve
// v is bf16 with row stride 1024 (the v half of the fused kv buffer).
// ---------------------------------------------------------------------------
__global__ __launch_bounds__(256) void gate_vt(const ushort* __restrict__ v,
                                               const float* __restrict__ x,
                                               const float* __restrict__ ve,
                                               const float* __restrict__ Wg,
                                               ushort* __restrict__ Vt) {
    const int t0 = blockIdx.x * 64, g = blockIdx.y, b = blockIdx.z;
    __shared__ float gateS[64];
    __shared__ ushort tile[128][66];   // [d][t], padded
    const int tid = threadIdx.x;
    if (tid < 64) {
        const float* xr = x + (size_t)(b * T_ + t0 + tid) * C_;
        float acc = 0.f;
        #pragma unroll
        for (int c = 0; c < 12; c++) acc += xr[c] * Wg[g * 12 + c];
        gateS[tid] = 3.0f / (1.0f + __expf(-acc));
    }
    __syncthreads();
    #pragma unroll
    for (int i = 0; i < 32; i++) {
        int idx = i * 256 + tid;       // 0..8191
        int r = idx >> 7;              // t within tile
        int d = idx & 127;
        size_t offv = (size_t)(b * T_ + t0 + r) * 1024 + g * D_ + d;
        size_t offe = (size_t)(b * T_ + t0 + r) * 512  + g * D_ + d;
        tile[d][r] = f2bf(bf2f(v[offv]) + gateS[r] * ve[offe]);
    }
    __syncthreads();
    ushort* ob = Vt + ((size_t)(b * KV_ + g) * D_) * T_ + t0;
    #pragma unroll
    for (int i = 0; i < 32; i++) {
        int idx = i * 256 + tid;
        int d = idx >> 6;              // 0..127
        int c = idx & 63;
        ob[(size_t)d * T_ + c] = tile[d][c];
    }
}

// ---------------------------------------------------------------------------
// Flash attention, 1 wave per (b, h, 16-query tile). mfma 16x16x32 bf16.
// Qp[b][h][t][d] (pre-scaled), Kp[b][g][s][d], Vt[b][g][d][s]; Y bf16 [b][t][h*D]
// ---------------------------------------------------------------------------
__global__ __launch_bounds__(64) void attn_mfma(const ushort* __restrict__ Qp,
                                                const ushort* __restrict__ Kp,
                                                const ushort* __restrict__ Vt,
                                                ushort* __restrict__ Y,
                                                const int* __restrict__ wptr) {
    const int t0 = blockIdx.x * 16;
    const int h  = blockIdx.y, b = blockIdx.z;
    const int g  = h / REP_;
    const int lane = threadIdx.x;
    const int m16 = lane & 15, quad = lane >> 4;
    __shared__ ushort Pl[16 * 40];

    const int w = *wptr;
    const bool windowed = (w >= 0 && w < T_);
    int s_lo = 0;
    if (windowed) { s_lo = t0 - w; if (s_lo < 0) s_lo = 0; }
    const int s_hi = t0 + 15;
    const int ss0 = s_lo & ~31;

    const ushort* qrow = Qp + ((size_t)(b * H_ + h) * T_ + t0 + m16) * D_ + quad * 8;
    bf16x8 qa[4];
    #pragma unroll
    for (int kc = 0; kc < 4; kc++) qa[kc] = ldb8(qrow + kc * 32);

    const ushort* kbase = Kp + (size_t)(b * KV_ + g) * T_ * D_;
    const ushort* vbase = Vt + (size_t)(b * KV_ + g) * D_ * T_;

    f32x4 o[8];
    #pragma unroll
    for (int dt = 0; dt < 8; dt++) o[dt] = (f32x4){0.f, 0.f, 0.f, 0.f};
    float mrow[4] = {-1e30f, -1e30f, -1e30f, -1e30f};
    float lrow[4] = {0.f, 0.f, 0.f, 0.f};

    for (int ss = ss0; ss <= s_hi; ss += 32) {
        f32x4 s0 = (f32x4){0.f,0.f,0.f,0.f};
        f32x4 s1 = (f32x4){0.f,0.f,0.f,0.f};
        const ushort* k0r = kbase + (size_t)(ss      + m16) * D_ + quad * 8;
        const ushort* k1r = kbase + (size_t)(ss + 16 + m16) * D_ + quad * 8;
        #pragma unroll
        for (int kc = 0; kc < 4; kc++) {
            bf16x8 kf0 = ldb8(k0r + kc * 32);
            bf16x8 kf1 = ldb8(k1r + kc * 32);
            s0 = __builtin_amdgcn_mfma_f32_16x16x32_bf16(qa[kc], kf0, s0, 0, 0, 0);
            s1 = __builtin_amdgcn_mfma_f32_16x16x32_bf16(qa[kc], kf1, s1, 0, 0, 0);
        }

        const int sA = ss + m16, sB = ss + 16 + m16;
        #pragma unroll
        for (int reg = 0; reg < 4; reg++) {
            const int t = t0 + quad * 4 + reg;
            const bool vA = (sA <= t) && (!windowed || (t - sA) <= w);
            const bool vB = (sB <= t) && (!windowed || (t - sB) <= w);
            float a  = vA ? s0[reg] : -1e30f;
            float bb = vB ? s1[reg] : -1e30f;
            float mt = fmaxf(a, bb);
            mt = fmaxf(mt, __shfl_xor(mt, 1));
            mt = fmaxf(mt, __shfl_xor(mt, 2));
            mt = fmaxf(mt, __shfl_xor(mt, 4));
            mt = fmaxf(mt, __shfl_xor(mt, 8));
            const float mnew  = fmaxf(mrow[reg], mt);
            const float alpha = __expf(mrow[reg] - mnew);
            mrow[reg] = mnew;
            const float pa = vA ? __expf(s0[reg] - mnew) : 0.f;
            const float pb = vB ? __expf(s1[reg] - mnew) : 0.f;
            float rs = pa + pb;
            rs += __shfl_xor(rs, 1);
            rs += __shfl_xor(rs, 2);
            rs += __shfl_xor(rs, 4);
            rs += __shfl_xor(rs, 8);
            lrow[reg] = lrow[reg] * alpha + rs;
            #pragma unroll
            for (int dt = 0; dt < 8; dt++) o[dt][reg] *= alpha;
            Pl[(quad * 4 + reg) * 40 + m16]      = f2bf(pa);
            Pl[(quad * 4 + reg) * 40 + 16 + m16] = f2bf(pb);
        }

        __syncthreads();
        bf16x8 pfrag = ldb8(&Pl[m16 * 40 + quad * 8]);
        __syncthreads();

        const ushort* vcol = vbase + (size_t)m16 * T_ + ss + quad * 8;
        #pragma unroll
        for (int dt = 0; dt < 8; dt++) {
            bf16x8 vf = ldb8(vcol + (size_t)(dt * 16) * T_);
            o[dt] = __builtin_amdgcn_mfma_f32_16x16x32_bf16(pfrag, vf, o[dt], 0, 0, 0);
        }
    }

    float inv[4];
    #pragma unroll
    for (int reg = 0; reg < 4; reg++) inv[reg] = 1.0f / lrow[reg];
    ushort* yb = Y + ((size_t)(b * T_ + t0 + quad * 4) * H_ + h) * D_ + m16;
    #pragma unroll
    for (int reg = 0; reg < 4; reg++)
        #pragma unroll
        for (int dt = 0; dt < 8; dt++)
            yb[(size_t)reg * H_ * D_ + dt * 16] = f2bf(o[dt][reg] * inv[reg]);
}

// ---------------------------------------------------------------------------
extern "C" void kernel_launch(void* const* d_in, const int* in_sizes, int n_in,
                              void* d_out, int out_size, void* d_ws, size_t ws_size,
                              hipStream_t stream) {
    const float* x     = (const float*)d_in[0];
    const float* ve    = (const float*)d_in[1];
    const float* cosb  = (const float*)d_in[2];
    const float* sinb  = (const float*)d_in[3];
    const float* Wq    = (const float*)d_in[4];
    const float* Wk    = (const float*)d_in[5];
    const float* Wv    = (const float*)d_in[6];
    const float* Wproj = (const float*)d_in[7];
    const float* Wg    = (const float*)d_in[8];
    const int*   wptr  = (const int*)d_in[9];
    float* out = (float*)d_out;

    // workspace layout (all bf16/ushort)
    ushort* xb   = (ushort*)d_ws;                   // M*C
    ushort* qb   = xb  + (size_t)M_ * C_;           // M*C   (later aliased: yb16)
    ushort* kvb  = qb  + (size_t)M_ * C_;           // M*1024 (later aliased: Wpb)
    ushort* Qp   = kvb + (size_t)M_ * 1024;         // M*C
    ushort* Kp   = Qp  + (size_t)M_ * C_;           // M*512
    ushort* Vt   = Kp  + (size_t)M_ * 512;          // M*512
    ushort* Wqb  = Vt  + (size_t)M_ * 512;          // C*C
    ushort* Wkvb = Wqb + (size_t)C_ * C_;           // 1024*C

    int n4;
    n4 = M_ * C_ / 4;
    cast_bf16<<<(n4 + 255) / 256, 256, 0, stream>>>(x, xb, n4);
    n4 = C_ * C_ / 4;
    cast_bf16<<<(n4 + 255) / 256, 256, 0, stream>>>(Wq, Wqb, n4);
    n4 = 512 * C_ / 4;
    cast_bf16<<<(n4 + 255) / 256, 256, 0, stream>>>(Wk, Wkvb, n4);
    cast_bf16<<<(n4 + 255) / 256, 256, 0, stream>>>(Wv, Wkvb + (size_t)512 * C_, n4);

    // projections (bf16 MFMA)
    gemm_bf16_bt<true><<<dim3(C_ / 128, M_ / 128), 256, 0, stream>>>(xb, Wqb, qb, M_, C_, C_);
    gemm_bf16_bt<true><<<dim3(1024 / 128, M_ / 128), 256, 0, stream>>>(xb, Wkvb, kvb, M_, 1024, C_);

    // ve-gate + transpose -> Vt (reads v half of kvb)
    gate_vt<<<dim3(T_ / 64, KV_, B_), 256, 0, stream>>>(kvb + 512, x, ve, Wg, Vt);

    // rope + rmsnorm -> packed bf16
    rope_rms_cast<<<M_ * H_, 64, 0, stream>>>(qb, Qp, cosb, sinb, H_, C_,
                                              1.2f * 1.2f * 0.08838834764831845f);
    rope_rms_cast<<<M_ * KV_, 64, 0, stream>>>(kvb, Kp, cosb, sinb, KV_, 1024, 1.0f);

    // Wproj cast (aliases kvb space — kvb fully consumed above)
    ushort* Wpb = kvb;
    n4 = C_ * C_ / 4;
    cast_bf16<<<(n4 + 255) / 256, 256, 0, stream>>>(Wproj, Wpb, n4);

    // flash attention -> yb16 (aliases qb space — qb consumed by rope)
    ushort* yb16 = qb;
    attn_mfma<<<dim3(T_ / 16, H_, B_), 64, 0, stream>>>(Qp, Kp, Vt, yb16, wptr);

    // out = y @ Wproj^T (fp32 out)
    gemm_bf16_bt<false><<<dim3(C_ / 128, M_ / 128), 256, 0, stream>>>(yb16, Wpb, out, M_, C_, C_);
}

// Round 4
// 373.720 us; speedup vs baseline: 11.1408x; 1.2194x over previous
//
#include <hip/hip_runtime.h>
#include <hip/hip_bf16.h>
#include <math.h>

// Problem constants
#define B_  2
#define T_  2048
#define C_  1536
#define H_  12
#define KV_ 4
#define D_  128
#define M_  (B_*T_)   // 4096 rows
#define REP_ (H_/KV_) // 3

typedef __bf16 bf16x8 __attribute__((ext_vector_type(8)));
typedef float  f32x4  __attribute__((ext_vector_type(4)));
typedef unsigned u32x4 __attribute__((ext_vector_type(4)));

union BCast { u32x4 u; bf16x8 b; };

__device__ inline bf16x8 ldb8(const ushort* p) {
    BCast c; c.u = *reinterpret_cast<const u32x4*>(p); return c.b;
}

__device__ inline ushort f2bf(float f) {
    union { float f; unsigned u; } v; v.f = f;
    unsigned u = v.u;
    return (ushort)((u + 0x7FFF + ((u >> 16) & 1)) >> 16);
}

__device__ inline float bf2f(ushort u) {
    union { unsigned u; float f; } v; v.u = (unsigned)u << 16;
    return v.f;
}

// async global->LDS, 16 bytes per lane; lds base must be wave-uniform
__device__ inline void async_copy16(const ushort* g, ushort* l) {
    __builtin_amdgcn_global_load_lds(
        (const __attribute__((address_space(1))) unsigned*)g,
        (__attribute__((address_space(3))) unsigned*)l, 16, 0, 0);
}

// ---------------------------------------------------------------------------
// bf16 MFMA GEMM (m97 structure): C[M,N] = A[M,K] * B[N,K]^T
// ---------------------------------------------------------------------------
template<bool BF16OUT>
__global__ __launch_bounds__(256) void gemm_bf16_bt(const ushort* __restrict__ A,
                                                    const ushort* __restrict__ Bm,
                                                    void* __restrict__ Cp,
                                                    int M, int N, int K) {
    __shared__ ushort As[128 * 32];
    __shared__ ushort Bs[128 * 32];
    const int tid  = threadIdx.x;
    const int wave = tid >> 6, lane = tid & 63;
    const int m16 = lane & 15, quad = lane >> 4;
    const int bm = blockIdx.y * 128, bn = blockIdx.x * 128;
    const int wm = (wave >> 1) * 64, wn = (wave & 1) * 64;

    const int lrow = lane >> 2;        // 0..15
    const int lcol = (lane & 3) * 8;   // 0,8,16,24
    const ushort* Ag = A  + (size_t)(bm + wave * 16 + lrow) * K + lcol;
    const ushort* Bg = Bm + (size_t)(bn + wave * 16 + lrow) * K + lcol;
    ushort* AsW0 = As + wave * 512;
    ushort* AsW1 = As + 2048 + wave * 512;
    ushort* BsW0 = Bs + wave * 512;
    ushort* BsW1 = Bs + 2048 + wave * 512;
    const size_t rowskip = (size_t)64 * K;

    f32x4 acc[4][4];
    #pragma unroll
    for (int i = 0; i < 4; i++)
        #pragma unroll
        for (int j = 0; j < 4; j++) acc[i][j] = (f32x4){0.f, 0.f, 0.f, 0.f};

    for (int k0 = 0; k0 < K; k0 += 32) {
        async_copy16(Ag + k0,           AsW0);
        async_copy16(Ag + k0 + rowskip, AsW1);
        async_copy16(Bg + k0,           BsW0);
        async_copy16(Bg + k0 + rowskip, BsW1);
        __syncthreads();

        bf16x8 af[4], bfr[4];
        #pragma unroll
        for (int i = 0; i < 4; i++)
            af[i] = ldb8(As + (wm + i * 16 + m16) * 32 + quad * 8);
        #pragma unroll
        for (int j = 0; j < 4; j++)
            bfr[j] = ldb8(Bs + (wn + j * 16 + m16) * 32 + quad * 8);
        #pragma unroll
        for (int i = 0; i < 4; i++)
            #pragma unroll
            for (int j = 0; j < 4; j++)
                acc[i][j] = __builtin_amdgcn_mfma_f32_16x16x32_bf16(af[i], bfr[j], acc[i][j], 0, 0, 0);
        __syncthreads();
    }

    #pragma unroll
    for (int i = 0; i < 4; i++) {
        #pragma unroll
        for (int reg = 0; reg < 4; reg++) {
            const int row = bm + wm + i * 16 + quad * 4 + reg;
            if constexpr (BF16OUT) {
                ushort* C = (ushort*)Cp;
                #pragma unroll
                for (int j = 0; j < 4; j++)
                    C[(size_t)row * N + bn + wn + j * 16 + m16] = f2bf(acc[i][j][reg]);
            } else {
                float* C = (float*)Cp;
                #pragma unroll
                for (int j = 0; j < 4; j++)
                    C[(size_t)row * N + bn + wn + j * 16 + m16] = acc[i][j][reg];
            }
        }
    }
}

// ---------------------------------------------------------------------------
// fp32 -> bf16 cast, 4 elements/thread
// ---------------------------------------------------------------------------
__global__ __launch_bounds__(256) void cast_bf16(const float* __restrict__ in,
                                                 ushort* __restrict__ out, int n4) {
    int i = blockIdx.x * 256 + threadIdx.x;
    if (i < n4) {
        float4 v = ((const float4*)in)[i];
        ushort4 o = make_ushort4(f2bf(v.x), f2bf(v.y), f2bf(v.z), f2bf(v.w));
        ((ushort4*)out)[i] = o;
    }
}

// ---------------------------------------------------------------------------
// RoPE + RMSNorm, bf16 in [bt*rowstride + h*128] -> bf16 out [((b*nh+h)*T+t)*128]
// ---------------------------------------------------------------------------
__global__ __launch_bounds__(64) void rope_rms_cast(const ushort* __restrict__ qk,
                                                    ushort* __restrict__ outp,
                                                    const float* __restrict__ cosb,
                                                    const float* __restrict__ sinb,
                                                    int nh, int rowstride, float outscale) {
    const int idx = blockIdx.x;       // (b*T+t)*nh + h
    const int bt = idx / nh;
    const int h  = idx - bt * nh;
    const int b  = bt >> 11;          // T_ = 2048
    const int t  = bt & (T_ - 1);
    const ushort* p = qk + (size_t)bt * rowstride + h * D_;
    const int i = threadIdx.x;        // 0..63
    const float x1 = bf2f(p[i]), x2 = bf2f(p[i + 64]);
    const float c = cosb[t * 64 + i], s = sinb[t * 64 + i];
    const float o1 =  x1 * c + x2 * s;
    const float o2 = -x1 * s + x2 * c;
    float ss = o1 * o1 + o2 * o2;
    #pragma unroll
    for (int off = 32; off > 0; off >>= 1) ss += __shfl_down(ss, off);
    ss = __shfl(ss, 0);
    const float scale = rsqrtf(ss * (1.0f / 128.0f) + 1.1920928955078125e-07f) * outscale;
    ushort* op = outp + ((size_t)(b * nh + h) * T_ + t) * D_;
    op[i]      = f2bf(o1 * scale);
    op[i + 64] = f2bf(o2 * scale);
}

// ---------------------------------------------------------------------------
// Fused ve-gate + transpose: Vt[b][g][d][s] = v[bt][g*128+d] + gate*ve
// ---------------------------------------------------------------------------
__global__ __launch_bounds__(256) void gate_vt(const ushort* __restrict__ v,
                                               const float* __restrict__ x,
                                               const float* __restrict__ ve,
                                               const float* __restrict__ Wg,
                                               ushort* __restrict__ Vt) {
    const int t0 = blockIdx.x * 64, g = blockIdx.y, b = blockIdx.z;
    __shared__ float gateS[64];
    __shared__ ushort tile[128][66];   // [d][t], padded
    const int tid = threadIdx.x;
    if (tid < 64) {
        const float* xr = x + (size_t)(b * T_ + t0 + tid) * C_;
        float acc = 0.f;
        #pragma unroll
        for (int c = 0; c < 12; c++) acc += xr[c] * Wg[g * 12 + c];
        gateS[tid] = 3.0f / (1.0f + __expf(-acc));
    }
    __syncthreads();
    #pragma unroll
    for (int i = 0; i < 32; i++) {
        int idx = i * 256 + tid;       // 0..8191
        int r = idx >> 7;              // t within tile
        int d = idx & 127;
        size_t offv = (size_t)(b * T_ + t0 + r) * 1024 + g * D_ + d;
        size_t offe = (size_t)(b * T_ + t0 + r) * 512  + g * D_ + d;
        tile[d][r] = f2bf(bf2f(v[offv]) + gateS[r] * ve[offe]);
    }
    __syncthreads();
    ushort* ob = Vt + ((size_t)(b * KV_ + g) * D_) * T_ + t0;
    #pragma unroll
    for (int i = 0; i < 32; i++) {
        int idx = i * 256 + tid;
        int d = idx >> 6;              // 0..127
        int c = idx & 63;
        ob[(size_t)d * T_ + c] = tile[d][c];
    }
}

// ---------------------------------------------------------------------------
// Flash attention v2: block = (b, h, 64 queries), 4 waves x 16 queries.
// K/V tiles (32 s-positions) staged cooperatively in LDS via global_load_lds.
// Ks layout [4 kc][32 s][32 d]  (row stride 64B, conflict-free ds_read_b128)
// Vs layout [128 d][32 s]       (row stride 64B, conflict-free)
// ---------------------------------------------------------------------------
__global__ __launch_bounds__(256) void attn_mfma(const ushort* __restrict__ Qp,
                                                 const ushort* __restrict__ Kp,
                                                 const ushort* __restrict__ Vt,
                                                 ushort* __restrict__ Y,
                                                 const int* __restrict__ wptr) {
    const int t0 = blockIdx.x * 64;
    const int h  = blockIdx.y, b = blockIdx.z;
    const int g  = h / REP_;
    const int tid  = threadIdx.x;
    const int wave = tid >> 6, lane = tid & 63;
    const int m16 = lane & 15, quad = lane >> 4;

    __shared__ ushort Ks[4 * 32 * 32];   // 8 KB
    __shared__ ushort Vs[128 * 32];      // 8 KB
    __shared__ ushort Pl[4][16 * 40];    // per-wave P buffers

    const int w = *wptr;
    const bool windowed = (w >= 0 && w < T_);
    int s_lo = 0;
    if (windowed) { s_lo = t0 - w; if (s_lo < 0) s_lo = 0; }
    const int s_hi = t0 + 63;
    const int ss0 = s_lo & ~31;
    const int tw = t0 + wave * 16;       // this wave's first query row

    // Q A-frags (global, once)
    const ushort* qrow = Qp + ((size_t)(b * H_ + h) * T_ + tw + m16) * D_ + quad * 8;
    bf16x8 qa[4];
    #pragma unroll
    for (int kc = 0; kc < 4; kc++) qa[kc] = ldb8(qrow + kc * 32);

    const ushort* kbase = Kp + (size_t)(b * KV_ + g) * T_ * D_;
    const ushort* vbase = Vt + (size_t)(b * KV_ + g) * D_ * T_;

    // staging addresses: this wave handles chunks cw and cw+4 (of 8) for K and V
    const int c0 = wave, c1 = wave + 4;
    // K chunk c: kc=c>>1, s_local=(c&1)*16 + (lane>>2), dcol=(c>>1)*32 + (lane&3)*8
    const ushort* kg0 = kbase + (size_t)((c0 & 1) * 16 + (lane >> 2)) * D_ + (c0 >> 1) * 32 + (lane & 3) * 8;
    const ushort* kg1 = kbase + (size_t)((c1 & 1) * 16 + (lane >> 2)) * D_ + (c1 >> 1) * 32 + (lane & 3) * 8;
    ushort* kl0 = Ks + c0 * 512;
    ushort* kl1 = Ks + c1 * 512;
    // V chunk c: d = c*16 + (lane>>2), col = (lane&3)*8
    const ushort* vg0 = vbase + (size_t)(c0 * 16 + (lane >> 2)) * T_ + (lane & 3) * 8;
    const ushort* vg1 = vbase + (size_t)(c1 * 16 + (lane >> 2)) * T_ + (lane & 3) * 8;
    ushort* vl0 = Vs + c0 * 512;
    ushort* vl1 = Vs + c1 * 512;

    f32x4 o[8];
    #pragma unroll
    for (int dt = 0; dt < 8; dt++) o[dt] = (f32x4){0.f, 0.f, 0.f, 0.f};
    float mrow[4] = {-1e30f, -1e30f, -1e30f, -1e30f};
    float lrow[4] = {0.f, 0.f, 0.f, 0.f};
    ushort* pw = &Pl[wave][0];

    for (int ss = ss0; ss <= s_hi; ss += 32) {
        // ---- cooperative staging ----
        const size_t koff = (size_t)ss * D_;
        async_copy16(kg0 + koff, kl0);
        async_copy16(kg1 + koff, kl1);
        async_copy16(vg0 + ss,   vl0);
        async_copy16(vg1 + ss,   vl1);
        __syncthreads();   // tile ready (barrier drains vmcnt)

        // ---- S = Q K^T (16 x 32) from LDS ----
        f32x4 s0 = (f32x4){0.f,0.f,0.f,0.f};
        f32x4 s1 = (f32x4){0.f,0.f,0.f,0.f};
        #pragma unroll
        for (int kc = 0; kc < 4; kc++) {
            bf16x8 kf0 = ldb8(Ks + kc * 1024 + m16 * 32 + quad * 8);
            bf16x8 kf1 = ldb8(Ks + kc * 1024 + (16 + m16) * 32 + quad * 8);
            s0 = __builtin_amdgcn_mfma_f32_16x16x32_bf16(qa[kc], kf0, s0, 0, 0, 0);
            s1 = __builtin_amdgcn_mfma_f32_16x16x32_bf16(qa[kc], kf1, s1, 0, 0, 0);
        }

        // ---- mask + online softmax ----
        const int sA = ss + m16, sB = ss + 16 + m16;
        #pragma unroll
        for (int reg = 0; reg < 4; reg++) {
            const int t = tw + quad * 4 + reg;
            const bool vA = (sA <= t) && (!windowed || (t - sA) <= w);
            const bool vB = (sB <= t) && (!windowed || (t - sB) <= w);
            float a  = vA ? s0[reg] : -1e30f;
            float bb = vB ? s1[reg] : -1e30f;
            float mt = fmaxf(a, bb);
            mt = fmaxf(mt, __shfl_xor(mt, 1));
            mt = fmaxf(mt, __shfl_xor(mt, 2));
            mt = fmaxf(mt, __shfl_xor(mt, 4));
            mt = fmaxf(mt, __shfl_xor(mt, 8));
            const float mnew  = fmaxf(mrow[reg], mt);
            const float alpha = __expf(mrow[reg] - mnew);
            mrow[reg] = mnew;
            const float pa = vA ? __expf(s0[reg] - mnew) : 0.f;
            const float pb = vB ? __expf(s1[reg] - mnew) : 0.f;
            float rs = pa + pb;
            rs += __shfl_xor(rs, 1);
            rs += __shfl_xor(rs, 2);
            rs += __shfl_xor(rs, 4);
            rs += __shfl_xor(rs, 8);
            lrow[reg] = lrow[reg] * alpha + rs;
            #pragma unroll
            for (int dt = 0; dt < 8; dt++) o[dt][reg] *= alpha;
            pw[(quad * 4 + reg) * 40 + m16]      = f2bf(pa);
            pw[(quad * 4 + reg) * 40 + 16 + m16] = f2bf(pb);
        }

        // ---- C-layout -> A-layout for P (per-wave buffer, lgkm wait only) ----
        __builtin_amdgcn_s_waitcnt(0xc07f);   // lgkmcnt(0), leave vmcnt alone
        bf16x8 pfrag = ldb8(pw + m16 * 40 + quad * 8);

        // ---- O += P V from LDS ----
        #pragma unroll
        for (int dt = 0; dt < 8; dt++) {
            bf16x8 vf = ldb8(Vs + (dt * 16 + m16) * 32 + quad * 8);
            o[dt] = __builtin_amdgcn_mfma_f32_16x16x32_bf16(pfrag, vf, o[dt], 0, 0, 0);
        }
        __syncthreads();   // all reads done before next stage overwrites
    }

    // ---- epilogue ----
    float inv[4];
    #pragma unroll
    for (int reg = 0; reg < 4; reg++) inv[reg] = 1.0f / lrow[reg];
    ushort* yb = Y + ((size_t)(b * T_ + tw + quad * 4) * H_ + h) * D_ + m16;
    #pragma unroll
    for (int reg = 0; reg < 4; reg++)
        #pragma unroll
        for (int dt = 0; dt < 8; dt++)
            yb[(size_t)reg * H_ * D_ + dt * 16] = f2bf(o[dt][reg] * inv[reg]);
}

// ---------------------------------------------------------------------------
extern "C" void kernel_launch(void* const* d_in, const int* in_sizes, int n_in,
                              void* d_out, int out_size, void* d_ws, size_t ws_size,
                              hipStream_t stream) {
    const float* x     = (const float*)d_in[0];
    const float* ve    = (const float*)d_in[1];
    const float* cosb  = (const float*)d_in[2];
    const float* sinb  = (const float*)d_in[3];
    const float* Wq    = (const float*)d_in[4];
    const float* Wk    = (const float*)d_in[5];
    const float* Wv    = (const float*)d_in[6];
    const float* Wproj = (const float*)d_in[7];
    const float* Wg    = (const float*)d_in[8];
    const int*   wptr  = (const int*)d_in[9];
    float* out = (float*)d_out;

    // workspace layout (all bf16/ushort)
    ushort* xb   = (ushort*)d_ws;                   // M*C
    ushort* qb   = xb  + (size_t)M_ * C_;           // M*C   (later aliased: yb16)
    ushort* kvb  = qb  + (size_t)M_ * C_;           // M*1024 (later aliased: Wpb)
    ushort* Qp   = kvb + (size_t)M_ * 1024;         // M*C
    ushort* Kp   = Qp  + (size_t)M_ * C_;           // M*512
    ushort* Vt   = Kp  + (size_t)M_ * 512;          // M*512
    ushort* Wqb  = Vt  + (size_t)M_ * 512;          // C*C
    ushort* Wkvb = Wqb + (size_t)C_ * C_;           // 1024*C

    int n4;
    n4 = M_ * C_ / 4;
    cast_bf16<<<(n4 + 255) / 256, 256, 0, stream>>>(x, xb, n4);
    n4 = C_ * C_ / 4;
    cast_bf16<<<(n4 + 255) / 256, 256, 0, stream>>>(Wq, Wqb, n4);
    n4 = 512 * C_ / 4;
    cast_bf16<<<(n4 + 255) / 256, 256, 0, stream>>>(Wk, Wkvb, n4);
    cast_bf16<<<(n4 + 255) / 256, 256, 0, stream>>>(Wv, Wkvb + (size_t)512 * C_, n4);

    // projections (bf16 MFMA)
    gemm_bf16_bt<true><<<dim3(C_ / 128, M_ / 128), 256, 0, stream>>>(xb, Wqb, qb, M_, C_, C_);
    gemm_bf16_bt<true><<<dim3(1024 / 128, M_ / 128), 256, 0, stream>>>(xb, Wkvb, kvb, M_, 1024, C_);

    // ve-gate + transpose -> Vt (reads v half of kvb)
    gate_vt<<<dim3(T_ / 64, KV_, B_), 256, 0, stream>>>(kvb + 512, x, ve, Wg, Vt);

    // rope + rmsnorm -> packed bf16
    rope_rms_cast<<<M_ * H_, 64, 0, stream>>>(qb, Qp, cosb, sinb, H_, C_,
                                              1.2f * 1.2f * 0.08838834764831845f);
    rope_rms_cast<<<M_ * KV_, 64, 0, stream>>>(kvb, Kp, cosb, sinb, KV_, 1024, 1.0f);

    // Wproj cast (aliases kvb space — kvb fully consumed above)
    ushort* Wpb = kvb;
    n4 = C_ * C_ / 4;
    cast_bf16<<<(n4 + 255) / 256, 256, 0, stream>>>(Wproj, Wpb, n4);

    // flash attention -> yb16 (aliases qb space — qb consumed by rope)
    ushort* yb16 = qb;
    attn_mfma<<<dim3(T_ / 64, H_, B_), 256, 0, stream>>>(Qp, Kp, Vt, yb16, wptr);

    // out = y @ Wproj^T (fp32 out)
    gemm_bf16_bt<false><<<dim3(C_ / 128, M_ / 128), 256, 0, stream>>>(yb16, Wpb, out, M_, C_, C_);
}

// Round 5
// 337.272 us; speedup vs baseline: 12.3447x; 1.1081x over previous
//
#include <hip/hip_runtime.h>
#include <hip/hip_bf16.h>
#include <math.h>

// Problem constants
#define B_  2
#define T_  2048
#define C_  1536
#define H_  12
#define KV_ 4
#define D_  128
#define M_  (B_*T_)   // 4096 rows
#define REP_ (H_/KV_) // 3

typedef __bf16 bf16x8 __attribute__((ext_vector_type(8)));
typedef float  f32x4  __attribute__((ext_vector_type(4)));
typedef unsigned u32x4 __attribute__((ext_vector_type(4)));

union BCast { u32x4 u; bf16x8 b; };

__device__ inline bf16x8 ldb8(const ushort* p) {
    BCast c; c.u = *reinterpret_cast<const u32x4*>(p); return c.b;
}

__device__ inline ushort f2bf(float f) {
    union { float f; unsigned u; } v; v.f = f;
    unsigned u = v.u;
    return (ushort)((u + 0x7FFF + ((u >> 16) & 1)) >> 16);
}

__device__ inline float bf2f(ushort u) {
    union { unsigned u; float f; } v; v.u = (unsigned)u << 16;
    return v.f;
}

// async global->LDS, 16 bytes per lane; lds base must be wave-uniform
__device__ inline void async_copy16(const ushort* g, ushort* l) {
    __builtin_amdgcn_global_load_lds(
        (const __attribute__((address_space(1))) unsigned*)g,
        (__attribute__((address_space(3))) unsigned*)l, 16, 0, 0);
}

// ---------------------------------------------------------------------------
// bf16 MFMA GEMM (m97 structure): C[M,N] = A[M,K] * B[N,K]^T
// ---------------------------------------------------------------------------
template<bool BF16OUT>
__global__ __launch_bounds__(256) void gemm_bf16_bt(const ushort* __restrict__ A,
                                                    const ushort* __restrict__ Bm,
                                                    void* __restrict__ Cp,
                                                    int M, int N, int K) {
    __shared__ ushort As[128 * 32];
    __shared__ ushort Bs[128 * 32];
    const int tid  = threadIdx.x;
    const int wave = tid >> 6, lane = tid & 63;
    const int m16 = lane & 15, quad = lane >> 4;
    const int bm = blockIdx.y * 128, bn = blockIdx.x * 128;
    const int wm = (wave >> 1) * 64, wn = (wave & 1) * 64;

    const int lrow = lane >> 2;        // 0..15
    const int lcol = (lane & 3) * 8;   // 0,8,16,24
    const ushort* Ag = A  + (size_t)(bm + wave * 16 + lrow) * K + lcol;
    const ushort* Bg = Bm + (size_t)(bn + wave * 16 + lrow) * K + lcol;
    ushort* AsW0 = As + wave * 512;
    ushort* AsW1 = As + 2048 + wave * 512;
    ushort* BsW0 = Bs + wave * 512;
    ushort* BsW1 = Bs + 2048 + wave * 512;
    const size_t rowskip = (size_t)64 * K;

    f32x4 acc[4][4];
    #pragma unroll
    for (int i = 0; i < 4; i++)
        #pragma unroll
        for (int j = 0; j < 4; j++) acc[i][j] = (f32x4){0.f, 0.f, 0.f, 0.f};

    for (int k0 = 0; k0 < K; k0 += 32) {
        async_copy16(Ag + k0,           AsW0);
        async_copy16(Ag + k0 + rowskip, AsW1);
        async_copy16(Bg + k0,           BsW0);
        async_copy16(Bg + k0 + rowskip, BsW1);
        __syncthreads();

        bf16x8 af[4], bfr[4];
        #pragma unroll
        for (int i = 0; i < 4; i++)
            af[i] = ldb8(As + (wm + i * 16 + m16) * 32 + quad * 8);
        #pragma unroll
        for (int j = 0; j < 4; j++)
            bfr[j] = ldb8(Bs + (wn + j * 16 + m16) * 32 + quad * 8);
        #pragma unroll
        for (int i = 0; i < 4; i++)
            #pragma unroll
            for (int j = 0; j < 4; j++)
                acc[i][j] = __builtin_amdgcn_mfma_f32_16x16x32_bf16(af[i], bfr[j], acc[i][j], 0, 0, 0);
        __syncthreads();
    }

    #pragma unroll
    for (int i = 0; i < 4; i++) {
        #pragma unroll
        for (int reg = 0; reg < 4; reg++) {
            const int row = bm + wm + i * 16 + quad * 4 + reg;
            if constexpr (BF16OUT) {
                ushort* C = (ushort*)Cp;
                #pragma unroll
                for (int j = 0; j < 4; j++)
                    C[(size_t)row * N + bn + wn + j * 16 + m16] = f2bf(acc[i][j][reg]);
            } else {
                float* C = (float*)Cp;
                #pragma unroll
                for (int j = 0; j < 4; j++)
                    C[(size_t)row * N + bn + wn + j * 16 + m16] = acc[i][j][reg];
            }
        }
    }
}

// ---------------------------------------------------------------------------
// fp32 -> bf16 cast, 4 elements/thread
// ---------------------------------------------------------------------------
__global__ __launch_bounds__(256) void cast_bf16(const float* __restrict__ in,
                                                 ushort* __restrict__ out, int n4) {
    int i = blockIdx.x * 256 + threadIdx.x;
    if (i < n4) {
        float4 v = ((const float4*)in)[i];
        ushort4 o = make_ushort4(f2bf(v.x), f2bf(v.y), f2bf(v.z), f2bf(v.w));
        ((ushort4*)out)[i] = o;
    }
}

// ---------------------------------------------------------------------------
// RoPE + RMSNorm, bf16 in [bt*rowstride + h*128] -> bf16 out [((b*nh+h)*T+t)*128]
// ---------------------------------------------------------------------------
__global__ __launch_bounds__(64) void rope_rms_cast(const ushort* __restrict__ qk,
                                                    ushort* __restrict__ outp,
                                                    const float* __restrict__ cosb,
                                                    const float* __restrict__ sinb,
                                                    int nh, int rowstride, float outscale) {
    const int idx = blockIdx.x;       // (b*T+t)*nh + h
    const int bt = idx / nh;
    const int h  = idx - bt * nh;
    const int b  = bt >> 11;          // T_ = 2048
    const int t  = bt & (T_ - 1);
    const ushort* p = qk + (size_t)bt * rowstride + h * D_;
    const int i = threadIdx.x;        // 0..63
    const float x1 = bf2f(p[i]), x2 = bf2f(p[i + 64]);
    const float c = cosb[t * 64 + i], s = sinb[t * 64 + i];
    const float o1 =  x1 * c + x2 * s;
    const float o2 = -x1 * s + x2 * c;
    float ss = o1 * o1 + o2 * o2;
    #pragma unroll
    for (int off = 32; off > 0; off >>= 1) ss += __shfl_down(ss, off);
    ss = __shfl(ss, 0);
    const float scale = rsqrtf(ss * (1.0f / 128.0f) + 1.1920928955078125e-07f) * outscale;
    ushort* op = outp + ((size_t)(b * nh + h) * T_ + t) * D_;
    op[i]      = f2bf(o1 * scale);
    op[i + 64] = f2bf(o2 * scale);
}

// ---------------------------------------------------------------------------
// Fused ve-gate + transpose: Vt[b][g][d][s] = v[bt][g*128+d] + gate*ve
// ---------------------------------------------------------------------------
__global__ __launch_bounds__(256) void gate_vt(const ushort* __restrict__ v,
                                               const float* __restrict__ x,
                                               const float* __restrict__ ve,
                                               const float* __restrict__ Wg,
                                               ushort* __restrict__ Vt) {
    const int t0 = blockIdx.x * 64, g = blockIdx.y, b = blockIdx.z;
    __shared__ float gateS[64];
    __shared__ ushort tile[128][66];   // [d][t], padded
    const int tid = threadIdx.x;
    if (tid < 64) {
        const float* xr = x + (size_t)(b * T_ + t0 + tid) * C_;
        float acc = 0.f;
        #pragma unroll
        for (int c = 0; c < 12; c++) acc += xr[c] * Wg[g * 12 + c];
        gateS[tid] = 3.0f / (1.0f + __expf(-acc));
    }
    __syncthreads();
    #pragma unroll
    for (int i = 0; i < 32; i++) {
        int idx = i * 256 + tid;       // 0..8191
        int r = idx >> 7;              // t within tile
        int d = idx & 127;
        size_t offv = (size_t)(b * T_ + t0 + r) * 1024 + g * D_ + d;
        size_t offe = (size_t)(b * T_ + t0 + r) * 512  + g * D_ + d;
        tile[d][r] = f2bf(bf2f(v[offv]) + gateS[r] * ve[offe]);
    }
    __syncthreads();
    ushort* ob = Vt + ((size_t)(b * KV_ + g) * D_) * T_ + t0;
    #pragma unroll
    for (int i = 0; i < 32; i++) {
        int idx = i * 256 + tid;
        int d = idx >> 6;              // 0..127
        int c = idx & 63;
        ob[(size_t)d * T_ + c] = tile[d][c];
    }
}

// ---------------------------------------------------------------------------
// Flash attention v3: block = (b, h, 64 queries), 2 waves x 32 queries.
// Static-max softmax (scores bounded by 1.44*sqrt(128) ~ 16.3 => exp(s) safe).
// l computed via ones-MFMA (exactly consistent with bf16 P).
// Ks [4 kc][32 s][32 d], Vs [128 d][32 s] staged via global_load_lds.
// ---------------------------------------------------------------------------
__global__ __launch_bounds__(128, 2) void attn_mfma(const ushort* __restrict__ Qp,
                                                    const ushort* __restrict__ Kp,
                                                    const ushort* __restrict__ Vt,
                                                    ushort* __restrict__ Y,
                                                    const int* __restrict__ wptr) {
    const int t0 = blockIdx.x * 64;
    const int h  = blockIdx.y, b = blockIdx.z;
    const int g  = h / REP_;
    const int tid  = threadIdx.x;
    const int wave = tid >> 6, lane = tid & 63;
    const int m16 = lane & 15, quad = lane >> 4;

    __shared__ ushort Ks[4 * 32 * 32];   // 8 KB
    __shared__ ushort Vs[128 * 32];      // 8 KB
    __shared__ ushort Pl[2][32 * 40];    // 5 KB, per-wave P buffers (32 rows)

    const int w = *wptr;
    const bool windowed = (w >= 0 && w < T_);
    const unsigned wu = windowed ? (unsigned)w : 0x7FFFFFFFu;
    int s_lo = 0;
    if (windowed) { s_lo = t0 - w; if (s_lo < 0) s_lo = 0; }
    const int s_hi = t0 + 63;
    const int ss0 = s_lo & ~31;
    const int tw = t0 + wave * 32;       // this wave's first query row

    // Q A-frags (global, once): 2 m-tiles x 4 k-chunks
    bf16x8 qa[2][4];
    #pragma unroll
    for (int mt = 0; mt < 2; mt++) {
        const ushort* qrow = Qp + ((size_t)(b * H_ + h) * T_ + tw + mt * 16 + m16) * D_ + quad * 8;
        #pragma unroll
        for (int kc = 0; kc < 4; kc++) qa[mt][kc] = ldb8(qrow + kc * 32);
    }

    const ushort* kbase = Kp + (size_t)(b * KV_ + g) * T_ * D_;
    const ushort* vbase = Vt + (size_t)(b * KV_ + g) * D_ * T_;

    // staging: wave handles K chunks 4w..4w+3 and V chunks 4w..4w+3 (1 KB each)
    const ushort* kg[4]; ushort* kl[4];
    const ushort* vg[4]; ushort* vl[4];
    #pragma unroll
    for (int i = 0; i < 4; i++) {
        const int c = wave * 4 + i;
        // K chunk c: kc=c>>1, s_local=(c&1)*16+(lane>>2), d=(c>>1)*32+(lane&3)*8
        kg[i] = kbase + (size_t)((c & 1) * 16 + (lane >> 2)) * D_ + (c >> 1) * 32 + (lane & 3) * 8;
        kl[i] = Ks + c * 512;
        // V chunk c: d = c*16 + (lane>>2), col=(lane&3)*8
        vg[i] = vbase + (size_t)(c * 16 + (lane >> 2)) * T_ + (lane & 3) * 8;
        vl[i] = Vs + c * 512;
    }

    f32x4 o[2][8];
    f32x4 lacc[2];
    #pragma unroll
    for (int mt = 0; mt < 2; mt++) {
        lacc[mt] = (f32x4){0.f, 0.f, 0.f, 0.f};
        #pragma unroll
        for (int dt = 0; dt < 8; dt++) o[mt][dt] = (f32x4){0.f, 0.f, 0.f, 0.f};
    }
    BCast onesc; onesc.u = (u32x4){0x3F803F80u, 0x3F803F80u, 0x3F803F80u, 0x3F803F80u};
    const bf16x8 ones = onesc.b;
    ushort* pw = &Pl[wave][0];

    for (int ss = ss0; ss <= s_hi; ss += 32) {
        // ---- cooperative staging ----
        const size_t koff = (size_t)ss * D_;
        #pragma unroll
        for (int i = 0; i < 4; i++) async_copy16(kg[i] + koff, kl[i]);
        #pragma unroll
        for (int i = 0; i < 4; i++) async_copy16(vg[i] + ss, vl[i]);
        __syncthreads();   // tile ready (barrier drains vmcnt)

        // ---- S = Q K^T (32 q x 32 s) from LDS; K frags shared across m-tiles ----
        f32x4 sc[2][2];
        #pragma unroll
        for (int mt = 0; mt < 2; mt++)
            #pragma unroll
            for (int hf = 0; hf < 2; hf++) sc[mt][hf] = (f32x4){0.f,0.f,0.f,0.f};
        #pragma unroll
        for (int kc = 0; kc < 4; kc++) {
            bf16x8 kf0 = ldb8(Ks + kc * 1024 + m16 * 32 + quad * 8);
            bf16x8 kf1 = ldb8(Ks + kc * 1024 + (16 + m16) * 32 + quad * 8);
            sc[0][0] = __builtin_amdgcn_mfma_f32_16x16x32_bf16(qa[0][kc], kf0, sc[0][0], 0, 0, 0);
            sc[0][1] = __builtin_amdgcn_mfma_f32_16x16x32_bf16(qa[0][kc], kf1, sc[0][1], 0, 0, 0);
            sc[1][0] = __builtin_amdgcn_mfma_f32_16x16x32_bf16(qa[1][kc], kf0, sc[1][0], 0, 0, 0);
            sc[1][1] = __builtin_amdgcn_mfma_f32_16x16x32_bf16(qa[1][kc], kf1, sc[1][1], 0, 0, 0);
        }

        // ---- mask + exp (static max; no shuffles, no rescale) ----
        #pragma unroll
        for (int mt = 0; mt < 2; mt++) {
            #pragma unroll
            for (int hf = 0; hf < 2; hf++) {
                const int sA = ss + hf * 16 + m16;
                #pragma unroll
                for (int reg = 0; reg < 4; reg++) {
                    const int t = tw + mt * 16 + quad * 4 + reg;
                    const bool valid = ((unsigned)(t - sA)) <= wu;
                    const float p = valid ? __expf(sc[mt][hf][reg]) : 0.f;
                    pw[(mt * 16 + quad * 4 + reg) * 40 + hf * 16 + m16] = f2bf(p);
                }
            }
        }

        // ---- C-layout -> A-layout for P (per-wave buffer, lgkm wait only) ----
        __builtin_amdgcn_s_waitcnt(0xc07f);   // lgkmcnt(0), leave vmcnt alone
        bf16x8 pf0 = ldb8(pw + m16 * 40 + quad * 8);
        bf16x8 pf1 = ldb8(pw + (16 + m16) * 40 + quad * 8);

        // ---- O += P V; l += P 1 (V frags shared across m-tiles) ----
        #pragma unroll
        for (int dt = 0; dt < 8; dt++) {
            bf16x8 vf = ldb8(Vs + (dt * 16 + m16) * 32 + quad * 8);
            o[0][dt] = __builtin_amdgcn_mfma_f32_16x16x32_bf16(pf0, vf, o[0][dt], 0, 0, 0);
            o[1][dt] = __builtin_amdgcn_mfma_f32_16x16x32_bf16(pf1, vf, o[1][dt], 0, 0, 0);
        }
        lacc[0] = __builtin_amdgcn_mfma_f32_16x16x32_bf16(pf0, ones, lacc[0], 0, 0, 0);
        lacc[1] = __builtin_amdgcn_mfma_f32_16x16x32_bf16(pf1, ones, lacc[1], 0, 0, 0);
        __syncthreads();   // all LDS reads done before next stage overwrites
    }

    // ---- epilogue: y = O / l ----
    #pragma unroll
    for (int mt = 0; mt < 2; mt++) {
        float inv[4];
        #pragma unroll
        for (int reg = 0; reg < 4; reg++) inv[reg] = 1.0f / lacc[mt][reg];
        ushort* yb = Y + ((size_t)(b * T_ + tw + mt * 16 + quad * 4) * H_ + h) * D_ + m16;
        #pragma unroll
        for (int reg = 0; reg < 4; reg++)
            #pragma unroll
            for (int dt = 0; dt < 8; dt++)
                yb[(size_t)reg * H_ * D_ + dt * 16] = f2bf(o[mt][dt][reg] * inv[reg]);
    }
}

// ---------------------------------------------------------------------------
extern "C" void kernel_launch(void* const* d_in, const int* in_sizes, int n_in,
                              void* d_out, int out_size, void* d_ws, size_t ws_size,
                              hipStream_t stream) {
    const float* x     = (const float*)d_in[0];
    const float* ve    = (const float*)d_in[1];
    const float* cosb  = (const float*)d_in[2];
    const float* sinb  = (const float*)d_in[3];
    const float* Wq    = (const float*)d_in[4];
    const float* Wk    = (const float*)d_in[5];
    const float* Wv    = (const float*)d_in[6];
    const float* Wproj = (const float*)d_in[7];
    const float* Wg    = (const float*)d_in[8];
    const int*   wptr  = (const int*)d_in[9];
    float* out = (float*)d_out;

    // workspace layout (all bf16/ushort)
    ushort* xb   = (ushort*)d_ws;                   // M*C
    ushort* qb   = xb  + (size_t)M_ * C_;           // M*C   (later aliased: yb16)
    ushort* kvb  = qb  + (size_t)M_ * C_;           // M*1024 (later aliased: Wpb)
    ushort* Qp   = kvb + (size_t)M_ * 1024;         // M*C
    ushort* Kp   = Qp  + (size_t)M_ * C_;           // M*512
    ushort* Vt   = Kp  + (size_t)M_ * 512;          // M*512
    ushort* Wqb  = Vt  + (size_t)M_ * 512;          // C*C
    ushort* Wkvb = Wqb + (size_t)C_ * C_;           // 1024*C

    int n4;
    n4 = M_ * C_ / 4;
    cast_bf16<<<(n4 + 255) / 256, 256, 0, stream>>>(x, xb, n4);
    n4 = C_ * C_ / 4;
    cast_bf16<<<(n4 + 255) / 256, 256, 0, stream>>>(Wq, Wqb, n4);
    n4 = 512 * C_ / 4;
    cast_bf16<<<(n4 + 255) / 256, 256, 0, stream>>>(Wk, Wkvb, n4);
    cast_bf16<<<(n4 + 255) / 256, 256, 0, stream>>>(Wv, Wkvb + (size_t)512 * C_, n4);

    // projections (bf16 MFMA)
    gemm_bf16_bt<true><<<dim3(C_ / 128, M_ / 128), 256, 0, stream>>>(xb, Wqb, qb, M_, C_, C_);
    gemm_bf16_bt<true><<<dim3(1024 / 128, M_ / 128), 256, 0, stream>>>(xb, Wkvb, kvb, M_, 1024, C_);

    // ve-gate + transpose -> Vt (reads v half of kvb)
    gate_vt<<<dim3(T_ / 64, KV_, B_), 256, 0, stream>>>(kvb + 512, x, ve, Wg, Vt);

    // rope + rmsnorm -> packed bf16
    rope_rms_cast<<<M_ * H_, 64, 0, stream>>>(qb, Qp, cosb, sinb, H_, C_,
                                              1.2f * 1.2f * 0.08838834764831845f);
    rope_rms_cast<<<M_ * KV_, 64, 0, stream>>>(kvb, Kp, cosb, sinb, KV_, 1024, 1.0f);

    // Wproj cast (aliases kvb space — kvb fully consumed above)
    ushort* Wpb = kvb;
    n4 = C_ * C_ / 4;
    cast_bf16<<<(n4 + 255) / 256, 256, 0, stream>>>(Wproj, Wpb, n4);

    // flash attention -> yb16 (aliases qb space — qb consumed by rope)
    ushort* yb16 = qb;
    attn_mfma<<<dim3(T_ / 64, H_, B_), 128, 0, stream>>>(Qp, Kp, Vt, yb16, wptr);

    // out = y @ Wproj^T (fp32 out)
    gemm_bf16_bt<false><<<dim3(C_ / 128, M_ / 128), 256, 0, stream>>>(yb16, Wpb, out, M_, C_, C_);
}

// Round 6
// 285.534 us; speedup vs baseline: 14.5816x; 1.1812x over previous
//
#include <hip/hip_runtime.h>
#include <hip/hip_bf16.h>
#include <math.h>

// Problem constants
#define B_  2
#define T_  2048
#define C_  1536
#define H_  12
#define KV_ 4
#define D_  128
#define M_  (B_*T_)   // 4096 rows
#define REP_ (H_/KV_) // 3
#define NQKV_ 2560    // fused q|k|v output width

typedef __bf16 bf16x8 __attribute__((ext_vector_type(8)));
typedef float  f32x4  __attribute__((ext_vector_type(4)));
typedef unsigned u32x4 __attribute__((ext_vector_type(4)));

union BCast { u32x4 u; bf16x8 b; };

__device__ inline bf16x8 ldb8(const ushort* p) {
    BCast c; c.u = *reinterpret_cast<const u32x4*>(p); return c.b;
}

__device__ inline ushort f2bf(float f) {
    union { float f; unsigned u; } v; v.f = f;
    unsigned u = v.u;
    return (ushort)((u + 0x7FFF + ((u >> 16) & 1)) >> 16);
}

__device__ inline float bf2f(ushort u) {
    union { unsigned u; float f; } v; v.u = (unsigned)u << 16;
    return v.f;
}

// async global->LDS, 16 bytes per lane; lds base must be wave-uniform
__device__ inline void async_copy16(const ushort* g, ushort* l) {
    __builtin_amdgcn_global_load_lds(
        (const __attribute__((address_space(1))) unsigned*)g,
        (__attribute__((address_space(3))) unsigned*)l, 16, 0, 0);
}

// ---------------------------------------------------------------------------
// bf16 MFMA GEMM (m97 structure): C[M,N] = A[M,K] * B[N,K]^T
// ---------------------------------------------------------------------------
template<bool BF16OUT>
__global__ __launch_bounds__(256) void gemm_bf16_bt(const ushort* __restrict__ A,
                                                    const ushort* __restrict__ Bm,
                                                    void* __restrict__ Cp,
                                                    int M, int N, int K) {
    __shared__ ushort As[128 * 32];
    __shared__ ushort Bs[128 * 32];
    const int tid  = threadIdx.x;
    const int wave = tid >> 6, lane = tid & 63;
    const int m16 = lane & 15, quad = lane >> 4;
    const int bm = blockIdx.y * 128, bn = blockIdx.x * 128;
    const int wm = (wave >> 1) * 64, wn = (wave & 1) * 64;

    const int lrow = lane >> 2;        // 0..15
    const int lcol = (lane & 3) * 8;   // 0,8,16,24
    const ushort* Ag = A  + (size_t)(bm + wave * 16 + lrow) * K + lcol;
    const ushort* Bg = Bm + (size_t)(bn + wave * 16 + lrow) * K + lcol;
    ushort* AsW0 = As + wave * 512;
    ushort* AsW1 = As + 2048 + wave * 512;
    ushort* BsW0 = Bs + wave * 512;
    ushort* BsW1 = Bs + 2048 + wave * 512;
    const size_t rowskip = (size_t)64 * K;

    f32x4 acc[4][4];
    #pragma unroll
    for (int i = 0; i < 4; i++)
        #pragma unroll
        for (int j = 0; j < 4; j++) acc[i][j] = (f32x4){0.f, 0.f, 0.f, 0.f};

    for (int k0 = 0; k0 < K; k0 += 32) {
        async_copy16(Ag + k0,           AsW0);
        async_copy16(Ag + k0 + rowskip, AsW1);
        async_copy16(Bg + k0,           BsW0);
        async_copy16(Bg + k0 + rowskip, BsW1);
        __syncthreads();

        bf16x8 af[4], bfr[4];
        #pragma unroll
        for (int i = 0; i < 4; i++)
            af[i] = ldb8(As + (wm + i * 16 + m16) * 32 + quad * 8);
        #pragma unroll
        for (int j = 0; j < 4; j++)
            bfr[j] = ldb8(Bs + (wn + j * 16 + m16) * 32 + quad * 8);
        #pragma unroll
        for (int i = 0; i < 4; i++)
            #pragma unroll
            for (int j = 0; j < 4; j++)
                acc[i][j] = __builtin_amdgcn_mfma_f32_16x16x32_bf16(af[i], bfr[j], acc[i][j], 0, 0, 0);
        __syncthreads();
    }

    #pragma unroll
    for (int i = 0; i < 4; i++) {
        #pragma unroll
        for (int reg = 0; reg < 4; reg++) {
            const int row = bm + wm + i * 16 + quad * 4 + reg;
            if constexpr (BF16OUT) {
                ushort* C = (ushort*)Cp;
                #pragma unroll
                for (int j = 0; j < 4; j++)
                    C[(size_t)row * N + bn + wn + j * 16 + m16] = f2bf(acc[i][j][reg]);
            } else {
                float* C = (float*)Cp;
                #pragma unroll
                for (int j = 0; j < 4; j++)
                    C[(size_t)row * N + bn + wn + j * 16 + m16] = acc[i][j][reg];
            }
        }
    }
}

// ---------------------------------------------------------------------------
// Fused segmented fp32->bf16 cast of x, Wq, Wk, Wv, Wproj (one launch).
// Segment boundaries in float4 units (compile-time constants).
// ---------------------------------------------------------------------------
#define SEG0 1572864   // x      : 4096*1536/4
#define SEG1 2162688   // + Wq   : 1536*1536/4
#define SEG2 2359296   // + Wk   : 512*1536/4
#define SEG3 2555904   // + Wv   : 512*1536/4
#define SEG4 3145728   // + Wproj: 1536*1536/4
__global__ __launch_bounds__(256) void cast_all(const float* __restrict__ x,
                                                const float* __restrict__ Wq,
                                                const float* __restrict__ Wk,
                                                const float* __restrict__ Wv,
                                                const float* __restrict__ Wp,
                                                ushort* __restrict__ xb,
                                                ushort* __restrict__ Wqkvb,
                                                ushort* __restrict__ Wpb) {
    const int i = blockIdx.x * 256 + threadIdx.x;
    const float* src; ushort* dst; int off;
    if (i < SEG0)      { src = x;  dst = xb;                          off = 0; }
    else if (i < SEG1) { src = Wq; dst = Wqkvb;                       off = SEG0; }
    else if (i < SEG2) { src = Wk; dst = Wqkvb + (size_t)1536 * C_;   off = SEG1; }
    else if (i < SEG3) { src = Wv; dst = Wqkvb + (size_t)2048 * C_;   off = SEG2; }
    else               { src = Wp; dst = Wpb;                         off = SEG3; }
    const int j = i - off;
    float4 v = ((const float4*)src)[j];
    ((ushort4*)dst)[j] = make_ushort4(f2bf(v.x), f2bf(v.y), f2bf(v.z), f2bf(v.w));
}

// ---------------------------------------------------------------------------
// RoPE + RMSNorm, bf16 in [bt*rowstride + colbase + h*128] ->
//   bf16 out [((b*nh+h)*T + t)][128].  4 (bt,h) pairs per 256-thread block.
// ---------------------------------------------------------------------------
__global__ __launch_bounds__(256) void rope_rms_cast(const ushort* __restrict__ qk,
                                                     ushort* __restrict__ outp,
                                                     const float* __restrict__ cosb,
                                                     const float* __restrict__ sinb,
                                                     int nh, int rowstride, int colbase,
                                                     float outscale) {
    const int idx = blockIdx.x * 4 + (threadIdx.x >> 6);  // (b*T+t)*nh + h
    const int bt = idx / nh;
    const int h  = idx - bt * nh;
    const int b  = bt >> 11;          // T_ = 2048
    const int t  = bt & (T_ - 1);
    const ushort* p = qk + (size_t)bt * rowstride + colbase + h * D_;
    const int i = threadIdx.x & 63;   // lane
    const float x1 = bf2f(p[i]), x2 = bf2f(p[i + 64]);
    const float c = cosb[t * 64 + i], s = sinb[t * 64 + i];
    const float o1 =  x1 * c + x2 * s;
    const float o2 = -x1 * s + x2 * c;
    float ss = o1 * o1 + o2 * o2;
    #pragma unroll
    for (int off = 32; off > 0; off >>= 1) ss += __shfl_down(ss, off);
    ss = __shfl(ss, 0);
    const float scale = rsqrtf(ss * (1.0f / 128.0f) + 1.1920928955078125e-07f) * outscale;
    ushort* op = outp + ((size_t)(b * nh + h) * T_ + t) * D_;
    op[i]      = f2bf(o1 * scale);
    op[i + 64] = f2bf(o2 * scale);
}

// ---------------------------------------------------------------------------
// Fused ve-gate + transpose: Vt[b][g][d][s] = qkv[bt][2048+g*128+d] + gate*ve
// ---------------------------------------------------------------------------
__global__ __launch_bounds__(256) void gate_vt(const ushort* __restrict__ qkv,
                                               const float* __restrict__ x,
                                               const float* __restrict__ ve,
                                               const float* __restrict__ Wg,
                                               ushort* __restrict__ Vt) {
    const int t0 = blockIdx.x * 64, g = blockIdx.y, b = blockIdx.z;
    __shared__ float gateS[64];
    __shared__ ushort tile[128][66];   // [d][t], padded
    const int tid = threadIdx.x;
    if (tid < 64) {
        const float* xr = x + (size_t)(b * T_ + t0 + tid) * C_;
        float acc = 0.f;
        #pragma unroll
        for (int c = 0; c < 12; c++) acc += xr[c] * Wg[g * 12 + c];
        gateS[tid] = 3.0f / (1.0f + __expf(-acc));
    }
    __syncthreads();
    #pragma unroll
    for (int i = 0; i < 32; i++) {
        int idx = i * 256 + tid;       // 0..8191
        int r = idx >> 7;              // t within tile
        int d = idx & 127;
        size_t offv = (size_t)(b * T_ + t0 + r) * NQKV_ + 2048 + g * D_ + d;
        size_t offe = (size_t)(b * T_ + t0 + r) * 512   + g * D_ + d;
        tile[d][r] = f2bf(bf2f(qkv[offv]) + gateS[r] * ve[offe]);
    }
    __syncthreads();
    ushort* ob = Vt + ((size_t)(b * KV_ + g) * D_) * T_ + t0;
    #pragma unroll
    for (int i = 0; i < 32; i++) {
        int idx = i * 256 + tid;
        int d = idx >> 6;              // 0..127
        int c = idx & 63;
        ob[(size_t)d * T_ + c] = tile[d][c];
    }
}

// ---------------------------------------------------------------------------
// Flash attention v4: block = (b, h, 64 queries), 4 waves x 16 queries.
// Static-max softmax + ones-MFMA l (R5), cooperative LDS staging (R4 geometry).
// Ks [4 kc][32 s][32 d], Vs [128 d][32 s] staged via global_load_lds.
// ---------------------------------------------------------------------------
__global__ __launch_bounds__(256, 3) void attn_mfma(const ushort* __restrict__ Qp,
                                                    const ushort* __restrict__ Kp,
                                                    const ushort* __restrict__ Vt,
                                                    ushort* __restrict__ Y,
                                                    const int* __restrict__ wptr) {
    const int t0 = blockIdx.x * 64;
    const int h  = blockIdx.y, b = blockIdx.z;
    const int g  = h / REP_;
    const int tid  = threadIdx.x;
    const int wave = tid >> 6, lane = tid & 63;
    const int m16 = lane & 15, quad = lane >> 4;

    __shared__ ushort Ks[4 * 32 * 32];   // 8 KB
    __shared__ ushort Vs[128 * 32];      // 8 KB
    __shared__ ushort Pl[4][16 * 40];    // 5 KB, per-wave P buffers

    const int w = *wptr;
    const bool windowed = (w >= 0 && w < T_);
    const unsigned wu = windowed ? (unsigned)w : 0x7FFFFFFFu;
    int s_lo = 0;
    if (windowed) { s_lo = t0 - w; if (s_lo < 0) s_lo = 0; }
    const int s_hi = t0 + 63;
    const int ss0 = s_lo & ~31;
    const int tw = t0 + wave * 16;       // this wave's first query row

    // Q A-frags (global, once)
    const ushort* qrow = Qp + ((size_t)(b * H_ + h) * T_ + tw + m16) * D_ + quad * 8;
    bf16x8 qa[4];
    #pragma unroll
    for (int kc = 0; kc < 4; kc++) qa[kc] = ldb8(qrow + kc * 32);

    const ushort* kbase = Kp + (size_t)(b * KV_ + g) * T_ * D_;
    const ushort* vbase = Vt + (size_t)(b * KV_ + g) * D_ * T_;

    // staging: wave handles chunks wave and wave+4 (of 8) for K and V
    const int c0 = wave, c1 = wave + 4;
    const ushort* kg0 = kbase + (size_t)((c0 & 1) * 16 + (lane >> 2)) * D_ + (c0 >> 1) * 32 + (lane & 3) * 8;
    const ushort* kg1 = kbase + (size_t)((c1 & 1) * 16 + (lane >> 2)) * D_ + (c1 >> 1) * 32 + (lane & 3) * 8;
    ushort* kl0 = Ks + c0 * 512;
    ushort* kl1 = Ks + c1 * 512;
    const ushort* vg0 = vbase + (size_t)(c0 * 16 + (lane >> 2)) * T_ + (lane & 3) * 8;
    const ushort* vg1 = vbase + (size_t)(c1 * 16 + (lane >> 2)) * T_ + (lane & 3) * 8;
    ushort* vl0 = Vs + c0 * 512;
    ushort* vl1 = Vs + c1 * 512;

    f32x4 o[8];
    #pragma unroll
    for (int dt = 0; dt < 8; dt++) o[dt] = (f32x4){0.f, 0.f, 0.f, 0.f};
    f32x4 lacc = (f32x4){0.f, 0.f, 0.f, 0.f};
    BCast onesc; onesc.u = (u32x4){0x3F803F80u, 0x3F803F80u, 0x3F803F80u, 0x3F803F80u};
    const bf16x8 ones = onesc.b;
    ushort* pw = &Pl[wave][0];

    for (int ss = ss0; ss <= s_hi; ss += 32) {
        // ---- cooperative staging ----
        const size_t koff = (size_t)ss * D_;
        async_copy16(kg0 + koff, kl0);
        async_copy16(kg1 + koff, kl1);
        async_copy16(vg0 + ss,   vl0);
        async_copy16(vg1 + ss,   vl1);
        __syncthreads();   // tile ready (barrier drains vmcnt)

        // ---- S = Q K^T (16 x 32) from LDS ----
        f32x4 s0 = (f32x4){0.f,0.f,0.f,0.f};
        f32x4 s1 = (f32x4){0.f,0.f,0.f,0.f};
        #pragma unroll
        for (int kc = 0; kc < 4; kc++) {
            bf16x8 kf0 = ldb8(Ks + kc * 1024 + m16 * 32 + quad * 8);
            bf16x8 kf1 = ldb8(Ks + kc * 1024 + (16 + m16) * 32 + quad * 8);
            s0 = __builtin_amdgcn_mfma_f32_16x16x32_bf16(qa[kc], kf0, s0, 0, 0, 0);
            s1 = __builtin_amdgcn_mfma_f32_16x16x32_bf16(qa[kc], kf1, s1, 0, 0, 0);
        }

        // ---- mask + exp (static max; scores bounded by 1.44*sqrt(128)) ----
        const int sA = ss + m16, sB = ss + 16 + m16;
        #pragma unroll
        for (int reg = 0; reg < 4; reg++) {
            const int t = tw + quad * 4 + reg;
            const float pa = ((unsigned)(t - sA) <= wu) ? __expf(s0[reg]) : 0.f;
            const float pb = ((unsigned)(t - sB) <= wu) ? __expf(s1[reg]) : 0.f;
            pw[(quad * 4 + reg) * 40 + m16]      = f2bf(pa);
            pw[(quad * 4 + reg) * 40 + 16 + m16] = f2bf(pb);
        }

        // ---- C-layout -> A-layout for P (per-wave buffer, lgkm wait only) ----
        __builtin_amdgcn_s_waitcnt(0xc07f);   // lgkmcnt(0), leave vmcnt alone
        bf16x8 pfrag = ldb8(pw + m16 * 40 + quad * 8);

        // ---- O += P V; l += P 1 ----
        #pragma unroll
        for (int dt = 0; dt < 8; dt++) {
            bf16x8 vf = ldb8(Vs + (dt * 16 + m16) * 32 + quad * 8);
            o[dt] = __builtin_amdgcn_mfma_f32_16x16x32_bf16(pfrag, vf, o[dt], 0, 0, 0);
        }
        lacc = __builtin_amdgcn_mfma_f32_16x16x32_bf16(pfrag, ones, lacc, 0, 0, 0);
        __syncthreads();   // all LDS reads done before next stage overwrites
    }

    // ---- epilogue: y = O / l ----
    float inv[4];
    #pragma unroll
    for (int reg = 0; reg < 4; reg++) inv[reg] = 1.0f / lacc[reg];
    ushort* yb = Y + ((size_t)(b * T_ + tw + quad * 4) * H_ + h) * D_ + m16;
    #pragma unroll
    for (int reg = 0; reg < 4; reg++)
        #pragma unroll
        for (int dt = 0; dt < 8; dt++)
            yb[(size_t)reg * H_ * D_ + dt * 16] = f2bf(o[dt][reg] * inv[reg]);
}

// ---------------------------------------------------------------------------
extern "C" void kernel_launch(void* const* d_in, const int* in_sizes, int n_in,
                              void* d_out, int out_size, void* d_ws, size_t ws_size,
                              hipStream_t stream) {
    const float* x     = (const float*)d_in[0];
    const float* ve    = (const float*)d_in[1];
    const float* cosb  = (const float*)d_in[2];
    const float* sinb  = (const float*)d_in[3];
    const float* Wq    = (const float*)d_in[4];
    const float* Wk    = (const float*)d_in[5];
    const float* Wv    = (const float*)d_in[6];
    const float* Wproj = (const float*)d_in[7];
    const float* Wg    = (const float*)d_in[8];
    const int*   wptr  = (const int*)d_in[9];
    float* out = (float*)d_out;

    // workspace layout (all bf16/ushort), ~64 MB total
    ushort* xb    = (ushort*)d_ws;                    // M*C
    ushort* qkv   = xb    + (size_t)M_ * C_;          // M*2560 (later aliased: yb16)
    ushort* Qp    = qkv   + (size_t)M_ * NQKV_;       // M*C
    ushort* Kp    = Qp    + (size_t)M_ * C_;          // M*512
    ushort* Vt    = Kp    + (size_t)M_ * 512;         // M*512
    ushort* Wqkvb = Vt    + (size_t)M_ * 512;         // 2560*C
    ushort* Wpb   = Wqkvb + (size_t)NQKV_ * C_;       // C*C

    // fused cast of x + all weights (one launch)
    cast_all<<<SEG4 / 256, 256, 0, stream>>>(x, Wq, Wk, Wv, Wproj, xb, Wqkvb, Wpb);

    // fused q|k|v projection
    gemm_bf16_bt<true><<<dim3(NQKV_ / 128, M_ / 128), 256, 0, stream>>>(xb, Wqkvb, qkv, M_, NQKV_, C_);

    // ve-gate + transpose -> Vt (reads v cols of qkv)
    gate_vt<<<dim3(T_ / 64, KV_, B_), 256, 0, stream>>>(qkv, x, ve, Wg, Vt);

    // rope + rmsnorm -> packed bf16
    rope_rms_cast<<<M_ * H_ / 4, 256, 0, stream>>>(qkv, Qp, cosb, sinb, H_, NQKV_, 0,
                                                   1.2f * 1.2f * 0.08838834764831845f);
    rope_rms_cast<<<M_ * KV_ / 4, 256, 0, stream>>>(qkv, Kp, cosb, sinb, KV_, NQKV_, 1536, 1.0f);

    // flash attention -> yb16 (aliases qkv space — qkv consumed above)
    ushort* yb16 = qkv;
    attn_mfma<<<dim3(T_ / 64, H_, B_), 256, 0, stream>>>(Qp, Kp, Vt, yb16, wptr);

    // out = y @ Wproj^T (fp32 out)
    gemm_bf16_bt<false><<<dim3(C_ / 128, M_ / 128), 256, 0, stream>>>(yb16, Wpb, out, M_, C_, C_);
}

// Round 7
// 277.538 us; speedup vs baseline: 15.0017x; 1.0288x over previous
//
#include <hip/hip_runtime.h>
#include <hip/hip_bf16.h>
#include <math.h>

// Problem constants
#define B_  2
#define T_  2048
#define C_  1536
#define H_  12
#define KV_ 4
#define D_  128
#define M_  (B_*T_)   // 4096 rows
#define REP_ (H_/KV_) // 3
#define NQKV_ 2560    // fused q|k|v output width

typedef __bf16 bf16x8 __attribute__((ext_vector_type(8)));
typedef float  f32x4  __attribute__((ext_vector_type(4)));
typedef unsigned u32x4 __attribute__((ext_vector_type(4)));

union BCast { u32x4 u; bf16x8 b; };

__device__ inline bf16x8 ldb8(const ushort* p) {
    BCast c; c.u = *reinterpret_cast<const u32x4*>(p); return c.b;
}

__device__ inline ushort f2bf(float f) {
    union { float f; unsigned u; } v; v.f = f;
    unsigned u = v.u;
    return (ushort)((u + 0x7FFF + ((u >> 16) & 1)) >> 16);
}

__device__ inline float bf2f(ushort u) {
    union { unsigned u; float f; } v; v.u = (unsigned)u << 16;
    return v.f;
}

// async global->LDS, 16 bytes per lane; lds base must be wave-uniform
__device__ inline void async_copy16(const ushort* g, ushort* l) {
    __builtin_amdgcn_global_load_lds(
        (const __attribute__((address_space(1))) unsigned*)g,
        (__attribute__((address_space(3))) unsigned*)l, 16, 0, 0);
}

// d-permutation for rope-pair locality: swap middle two 32-blocks of each head.
// Applied to Wq AND Wk rows => QK^T unchanged; pairs (i,i+64) -> cols 32 apart.
__device__ __host__ inline int dperm(int d) {
    return (d < 32) ? d : (d < 64 ? d + 32 : (d < 96 ? d - 32 : d));
}

// ---------------------------------------------------------------------------
// bf16 MFMA GEMM (m97 structure): C[M,N] = A[M,K] * B[N,K]^T  (proj path)
// ---------------------------------------------------------------------------
template<bool BF16OUT>
__global__ __launch_bounds__(256) void gemm_bf16_bt(const ushort* __restrict__ A,
                                                    const ushort* __restrict__ Bm,
                                                    void* __restrict__ Cp,
                                                    int M, int N, int K) {
    __shared__ ushort As[128 * 32];
    __shared__ ushort Bs[128 * 32];
    const int tid  = threadIdx.x;
    const int wave = tid >> 6, lane = tid & 63;
    const int m16 = lane & 15, quad = lane >> 4;
    const int bm = blockIdx.y * 128, bn = blockIdx.x * 128;
    const int wm = (wave >> 1) * 64, wn = (wave & 1) * 64;

    const int lrow = lane >> 2;
    const int lcol = (lane & 3) * 8;
    const ushort* Ag = A  + (size_t)(bm + wave * 16 + lrow) * K + lcol;
    const ushort* Bg = Bm + (size_t)(bn + wave * 16 + lrow) * K + lcol;
    ushort* AsW0 = As + wave * 512;
    ushort* AsW1 = As + 2048 + wave * 512;
    ushort* BsW0 = Bs + wave * 512;
    ushort* BsW1 = Bs + 2048 + wave * 512;
    const size_t rowskip = (size_t)64 * K;

    f32x4 acc[4][4];
    #pragma unroll
    for (int i = 0; i < 4; i++)
        #pragma unroll
        for (int j = 0; j < 4; j++) acc[i][j] = (f32x4){0.f, 0.f, 0.f, 0.f};

    for (int k0 = 0; k0 < K; k0 += 32) {
        async_copy16(Ag + k0,           AsW0);
        async_copy16(Ag + k0 + rowskip, AsW1);
        async_copy16(Bg + k0,           BsW0);
        async_copy16(Bg + k0 + rowskip, BsW1);
        __syncthreads();

        bf16x8 af[4], bfr[4];
        #pragma unroll
        for (int i = 0; i < 4; i++)
            af[i] = ldb8(As + (wm + i * 16 + m16) * 32 + quad * 8);
        #pragma unroll
        for (int j = 0; j < 4; j++)
            bfr[j] = ldb8(Bs + (wn + j * 16 + m16) * 32 + quad * 8);
        #pragma unroll
        for (int i = 0; i < 4; i++)
            #pragma unroll
            for (int j = 0; j < 4; j++)
                acc[i][j] = __builtin_amdgcn_mfma_f32_16x16x32_bf16(af[i], bfr[j], acc[i][j], 0, 0, 0);
        __syncthreads();
    }

    #pragma unroll
    for (int i = 0; i < 4; i++) {
        #pragma unroll
        for (int reg = 0; reg < 4; reg++) {
            const int row = bm + wm + i * 16 + quad * 4 + reg;
            if constexpr (BF16OUT) {
                ushort* C = (ushort*)Cp;
                #pragma unroll
                for (int j = 0; j < 4; j++)
                    C[(size_t)row * N + bn + wn + j * 16 + m16] = f2bf(acc[i][j][reg]);
            } else {
                float* C = (float*)Cp;
                #pragma unroll
                for (int j = 0; j < 4; j++)
                    C[(size_t)row * N + bn + wn + j * 16 + m16] = acc[i][j][reg];
            }
        }
    }
}

// ---------------------------------------------------------------------------
// Fused QKV GEMM: C = xb @ Wqkvb^T (M=4096, N=2560, K=1536), epilogue by tile:
//   bn<1536   : q head h=bn/128 -> RMS(rope-invariant) + rope + *0.127.. -> Qp
//   1536..2047: k group          -> same, scale 1.0 -> Kp
//   >=2048    : v -> plain bf16 to vbuf[row][512]
// Qp/Kp are in PERMUTED d-order (dperm) — consistent for q&k => QK^T invariant.
// ---------------------------------------------------------------------------
#define KQ_ 1536
__global__ __launch_bounds__(256) void gemm_qkv(const ushort* __restrict__ A,
                                                const ushort* __restrict__ Bm,
                                                ushort* __restrict__ Qp,
                                                ushort* __restrict__ Kp,
                                                ushort* __restrict__ vbuf,
                                                const float* __restrict__ cosb,
                                                const float* __restrict__ sinb) {
    __shared__ ushort As[128 * 32];
    __shared__ ushort Bs[128 * 32];
    const int tid  = threadIdx.x;
    const int wave = tid >> 6, lane = tid & 63;
    const int m16 = lane & 15, quad = lane >> 4;
    const int bm = blockIdx.y * 128, bn = blockIdx.x * 128;
    const int wm = (wave >> 1) * 64, wn = (wave & 1) * 64;

    const int lrow = lane >> 2;
    const int lcol = (lane & 3) * 8;
    const ushort* Ag = A  + (size_t)(bm + wave * 16 + lrow) * KQ_ + lcol;
    const ushort* Bg = Bm + (size_t)(bn + wave * 16 + lrow) * KQ_ + lcol;
    ushort* AsW0 = As + wave * 512;
    ushort* AsW1 = As + 2048 + wave * 512;
    ushort* BsW0 = Bs + wave * 512;
    ushort* BsW1 = Bs + 2048 + wave * 512;
    const size_t rowskip = (size_t)64 * KQ_;

    f32x4 acc[4][4];
    #pragma unroll
    for (int i = 0; i < 4; i++)
        #pragma unroll
        for (int j = 0; j < 4; j++) acc[i][j] = (f32x4){0.f, 0.f, 0.f, 0.f};

    for (int k0 = 0; k0 < KQ_; k0 += 32) {
        async_copy16(Ag + k0,           AsW0);
        async_copy16(Ag + k0 + rowskip, AsW1);
        async_copy16(Bg + k0,           BsW0);
        async_copy16(Bg + k0 + rowskip, BsW1);
        __syncthreads();

        bf16x8 af[4], bfr[4];
        #pragma unroll
        for (int i = 0; i < 4; i++)
            af[i] = ldb8(As + (wm + i * 16 + m16) * 32 + quad * 8);
        #pragma unroll
        for (int j = 0; j < 4; j++)
            bfr[j] = ldb8(Bs + (wn + j * 16 + m16) * 32 + quad * 8);
        #pragma unroll
        for (int i = 0; i < 4; i++)
            #pragma unroll
            for (int j = 0; j < 4; j++)
                acc[i][j] = __builtin_amdgcn_mfma_f32_16x16x32_bf16(af[i], bfr[j], acc[i][j], 0, 0, 0);
        __syncthreads();
    }

    if (bn < 2048) {
        // ---- q/k tile: RMS (rotation-invariant, from raw acc) + rope ----
        float* ssqS = (float*)As;   // [128][2] floats, reuses dead As (1 KB)
        float ssq[4][4];
        #pragma unroll
        for (int i = 0; i < 4; i++) {
            #pragma unroll
            for (int reg = 0; reg < 4; reg++) {
                float v = acc[i][0][reg]*acc[i][0][reg] + acc[i][1][reg]*acc[i][1][reg]
                        + acc[i][2][reg]*acc[i][2][reg] + acc[i][3][reg]*acc[i][3][reg];
                v += __shfl_xor(v, 1); v += __shfl_xor(v, 2);
                v += __shfl_xor(v, 4); v += __shfl_xor(v, 8);
                ssq[i][reg] = v;    // this wave's 64-col half, all 16 m16-lanes agree
            }
        }
        if (m16 == 0) {
            #pragma unroll
            for (int i = 0; i < 4; i++)
                #pragma unroll
                for (int reg = 0; reg < 4; reg++)
                    ssqS[(wm + i*16 + quad*4 + reg) * 2 + (wave & 1)] = ssq[i][reg];
        }
        __syncthreads();

        const bool isq = (bn < 1536);
        const float osc = isq ? (1.2f * 1.2f * 0.08838834764831845f) : 1.0f;
        const int hh  = isq ? (bn >> 7) : ((bn - 1536) >> 7);
        const int nh  = isq ? H_ : KV_;
        ushort* outp  = isq ? Qp : Kp;

        float scl[4][4];
        #pragma unroll
        for (int i = 0; i < 4; i++) {
            #pragma unroll
            for (int reg = 0; reg < 4; reg++) {
                const int r = wm + i*16 + quad*4 + reg;
                const float tot = ssqS[r*2] + ssqS[r*2 + 1];
                scl[i][reg] = rsqrtf(tot * (1.0f/128.0f) + 1.1920928955078125e-07f) * osc;
            }
        }

        #pragma unroll
        for (int i = 0; i < 4; i++) {
            #pragma unroll
            for (int reg = 0; reg < 4; reg++) {
                const int row = bm + wm + i*16 + quad*4 + reg;
                const int b = row >> 11, t = row & (T_ - 1);
                ushort* orow = outp + ((size_t)(b * nh + hh) * T_ + t) * D_;
                const float sc = scl[i][reg];
                #pragma unroll
                for (int jp = 0; jp < 2; jp++) {
                    // local col c = jp*16+m16 holds orig pair index i = (wn?32:0)+c
                    const int ipair = (wn ? 32 : 0) + jp*16 + m16;
                    const float c = cosb[t*64 + ipair], s = sinb[t*64 + ipair];
                    const float x1 = acc[i][jp][reg], x2 = acc[i][jp+2][reg];
                    orow[wn + jp*16 + m16]       = f2bf((x1*c + x2*s) * sc);
                    orow[wn + (jp+2)*16 + m16]   = f2bf((x2*c - x1*s) * sc);
                }
            }
        }
    } else {
        // ---- v tile: plain bf16 to vbuf [row][512] (original d-order) ----
        const int cb = bn - 2048 + wn;
        #pragma unroll
        for (int i = 0; i < 4; i++) {
            #pragma unroll
            for (int reg = 0; reg < 4; reg++) {
                const int row = bm + wm + i*16 + quad*4 + reg;
                ushort* vr = vbuf + (size_t)row * 512 + cb + m16;
                #pragma unroll
                for (int j = 0; j < 4; j++)
                    vr[j*16] = f2bf(acc[i][j][reg]);
            }
        }
    }
}

// ---------------------------------------------------------------------------
// Fused segmented fp32->bf16 cast of x, Wq, Wk, Wv, Wproj (one launch).
// Wq/Wk rows are written in dperm order (rope-pair locality).
// ---------------------------------------------------------------------------
#define SEG0 1572864   // x      : 4096*1536/4
#define SEG1 2162688   // + Wq   : 1536*1536/4
#define SEG2 2359296   // + Wk   : 512*1536/4
#define SEG3 2555904   // + Wv   : 512*1536/4
#define SEG4 3145728   // + Wproj: 1536*1536/4
#define ROW4 384       // float4s per 1536-col row
__global__ __launch_bounds__(256) void cast_all(const float* __restrict__ x,
                                                const float* __restrict__ Wq,
                                                const float* __restrict__ Wk,
                                                const float* __restrict__ Wv,
                                                const float* __restrict__ Wp,
                                                ushort* __restrict__ xb,
                                                ushort* __restrict__ Wqkvb,
                                                ushort* __restrict__ Wpb) {
    const int i = blockIdx.x * 256 + threadIdx.x;
    float4 v; size_t dst4; ushort* dstp;
    if (i < SEG0) {
        v = ((const float4*)x)[i]; dstp = xb; dst4 = i;
    } else if (i < SEG1) {
        const int j = i - SEG0;
        const int r = j / ROW4, c4 = j - r * ROW4;
        const int d = r & 127, hh = r >> 7;
        v = ((const float4*)Wq)[j]; dstp = Wqkvb;
        dst4 = (size_t)(hh * 128 + dperm(d)) * ROW4 + c4;
    } else if (i < SEG2) {
        const int j = i - SEG1;
        const int r = j / ROW4, c4 = j - r * ROW4;
        const int d = r & 127, g = r >> 7;
        v = ((const float4*)Wk)[j]; dstp = Wqkvb;
        dst4 = (size_t)(1536 + g * 128 + dperm(d)) * ROW4 + c4;
    } else if (i < SEG3) {
        const int j = i - SEG2;
        v = ((const float4*)Wv)[j]; dstp = Wqkvb;
        dst4 = (size_t)2048 * ROW4 + j;
    } else {
        const int j = i - SEG3;
        v = ((const float4*)Wp)[j]; dstp = Wpb; dst4 = j;
    }
    ((ushort4*)dstp)[dst4] = make_ushort4(f2bf(v.x), f2bf(v.y), f2bf(v.z), f2bf(v.w));
}

// ---------------------------------------------------------------------------
// Fused ve-gate + transpose: Vt[b][g][d][s] = vbuf[bt][g*128+d] + gate*ve
// ---------------------------------------------------------------------------
__global__ __launch_bounds__(256) void gate_vt(const ushort* __restrict__ vbuf,
                                               const float* __restrict__ x,
                                               const float* __restrict__ ve,
                                               const float* __restrict__ Wg,
                                               ushort* __restrict__ Vt) {
    const int t0 = blockIdx.x * 64, g = blockIdx.y, b = blockIdx.z;
    __shared__ float gateS[64];
    __shared__ ushort tile[128][66];   // [d][t], padded
    const int tid = threadIdx.x;
    if (tid < 64) {
        const float* xr = x + (size_t)(b * T_ + t0 + tid) * C_;
        float acc = 0.f;
        #pragma unroll
        for (int c = 0; c < 12; c++) acc += xr[c] * Wg[g * 12 + c];
        gateS[tid] = 3.0f / (1.0f + __expf(-acc));
    }
    __syncthreads();
    #pragma unroll
    for (int i = 0; i < 32; i++) {
        int idx = i * 256 + tid;       // 0..8191
        int r = idx >> 7;              // t within tile
        int d = idx & 127;
        size_t offv = (size_t)(b * T_ + t0 + r) * 512 + g * D_ + d;
        tile[d][r] = f2bf(bf2f(vbuf[offv]) + gateS[r] * ve[offv]);
    }
    __syncthreads();
    ushort* ob = Vt + ((size_t)(b * KV_ + g) * D_) * T_ + t0;
    #pragma unroll
    for (int i = 0; i < 32; i++) {
        int idx = i * 256 + tid;
        int d = idx >> 6;              // 0..127
        int c = idx & 63;
        ob[(size_t)d * T_ + c] = tile[d][c];
    }
}

// ---------------------------------------------------------------------------
// Flash attention: block = (b, h, 64 queries), 4 waves x 16 queries.
// Static-max softmax + ones-MFMA l; K/V staged via global_load_lds.
// ---------------------------------------------------------------------------
__global__ __launch_bounds__(256, 3) void attn_mfma(const ushort* __restrict__ Qp,
                                                    const ushort* __restrict__ Kp,
                                                    const ushort* __restrict__ Vt,
                                                    ushort* __restrict__ Y,
                                                    const int* __restrict__ wptr) {
    const int t0 = blockIdx.x * 64;
    const int h  = blockIdx.y, b = blockIdx.z;
    const int g  = h / REP_;
    const int tid  = threadIdx.x;
    const int wave = tid >> 6, lane = tid & 63;
    const int m16 = lane & 15, quad = lane >> 4;

    __shared__ ushort Ks[4 * 32 * 32];   // 8 KB
    __shared__ ushort Vs[128 * 32];      // 8 KB
    __shared__ ushort Pl[4][16 * 40];    // 5 KB, per-wave P buffers

    const int w = *wptr;
    const bool windowed = (w >= 0 && w < T_);
    const unsigned wu = windowed ? (unsigned)w : 0x7FFFFFFFu;
    int s_lo = 0;
    if (windowed) { s_lo = t0 - w; if (s_lo < 0) s_lo = 0; }
    const int s_hi = t0 + 63;
    const int ss0 = s_lo & ~31;
    const int tw = t0 + wave * 16;

    const ushort* qrow = Qp + ((size_t)(b * H_ + h) * T_ + tw + m16) * D_ + quad * 8;
    bf16x8 qa[4];
    #pragma unroll
    for (int kc = 0; kc < 4; kc++) qa[kc] = ldb8(qrow + kc * 32);

    const ushort* kbase = Kp + (size_t)(b * KV_ + g) * T_ * D_;
    const ushort* vbase = Vt + (size_t)(b * KV_ + g) * D_ * T_;

    const int c0 = wave, c1 = wave + 4;
    const ushort* kg0 = kbase + (size_t)((c0 & 1) * 16 + (lane >> 2)) * D_ + (c0 >> 1) * 32 + (lane & 3) * 8;
    const ushort* kg1 = kbase + (size_t)((c1 & 1) * 16 + (lane >> 2)) * D_ + (c1 >> 1) * 32 + (lane & 3) * 8;
    ushort* kl0 = Ks + c0 * 512;
    ushort* kl1 = Ks + c1 * 512;
    const ushort* vg0 = vbase + (size_t)(c0 * 16 + (lane >> 2)) * T_ + (lane & 3) * 8;
    const ushort* vg1 = vbase + (size_t)(c1 * 16 + (lane >> 2)) * T_ + (lane & 3) * 8;
    ushort* vl0 = Vs + c0 * 512;
    ushort* vl1 = Vs + c1 * 512;

    f32x4 o[8];
    #pragma unroll
    for (int dt = 0; dt < 8; dt++) o[dt] = (f32x4){0.f, 0.f, 0.f, 0.f};
    f32x4 lacc = (f32x4){0.f, 0.f, 0.f, 0.f};
    BCast onesc; onesc.u = (u32x4){0x3F803F80u, 0x3F803F80u, 0x3F803F80u, 0x3F803F80u};
    const bf16x8 ones = onesc.b;
    ushort* pw = &Pl[wave][0];

    for (int ss = ss0; ss <= s_hi; ss += 32) {
        const size_t koff = (size_t)ss * D_;
        async_copy16(kg0 + koff, kl0);
        async_copy16(kg1 + koff, kl1);
        async_copy16(vg0 + ss,   vl0);
        async_copy16(vg1 + ss,   vl1);
        __syncthreads();

        f32x4 s0 = (f32x4){0.f,0.f,0.f,0.f};
        f32x4 s1 = (f32x4){0.f,0.f,0.f,0.f};
        #pragma unroll
        for (int kc = 0; kc < 4; kc++) {
            bf16x8 kf0 = ldb8(Ks + kc * 1024 + m16 * 32 + quad * 8);
            bf16x8 kf1 = ldb8(Ks + kc * 1024 + (16 + m16) * 32 + quad * 8);
            s0 = __builtin_amdgcn_mfma_f32_16x16x32_bf16(qa[kc], kf0, s0, 0, 0, 0);
            s1 = __builtin_amdgcn_mfma_f32_16x16x32_bf16(qa[kc], kf1, s1, 0, 0, 0);
        }

        const int sA = ss + m16, sB = ss + 16 + m16;
        #pragma unroll
        for (int reg = 0; reg < 4; reg++) {
            const int t = tw + quad * 4 + reg;
            const float pa = ((unsigned)(t - sA) <= wu) ? __expf(s0[reg]) : 0.f;
            const float pb = ((unsigned)(t - sB) <= wu) ? __expf(s1[reg]) : 0.f;
            pw[(quad * 4 + reg) * 40 + m16]      = f2bf(pa);
            pw[(quad * 4 + reg) * 40 + 16 + m16] = f2bf(pb);
        }

        __builtin_amdgcn_s_waitcnt(0xc07f);   // lgkmcnt(0), leave vmcnt alone
        bf16x8 pfrag = ldb8(pw + m16 * 40 + quad * 8);

        #pragma unroll
        for (int dt = 0; dt < 8; dt++) {
            bf16x8 vf = ldb8(Vs + (dt * 16 + m16) * 32 + quad * 8);
            o[dt] = __builtin_amdgcn_mfma_f32_16x16x32_bf16(pfrag, vf, o[dt], 0, 0, 0);
        }
        lacc = __builtin_amdgcn_mfma_f32_16x16x32_bf16(pfrag, ones, lacc, 0, 0, 0);
        __syncthreads();
    }

    float inv[4];
    #pragma unroll
    for (int reg = 0; reg < 4; reg++) inv[reg] = 1.0f / lacc[reg];
    ushort* yb = Y + ((size_t)(b * T_ + tw + quad * 4) * H_ + h) * D_ + m16;
    #pragma unroll
    for (int reg = 0; reg < 4; reg++)
        #pragma unroll
        for (int dt = 0; dt < 8; dt++)
            yb[(size_t)reg * H_ * D_ + dt * 16] = f2bf(o[dt][reg] * inv[reg]);
}

// ---------------------------------------------------------------------------
extern "C" void kernel_launch(void* const* d_in, const int* in_sizes, int n_in,
                              void* d_out, int out_size, void* d_ws, size_t ws_size,
                              hipStream_t stream) {
    const float* x     = (const float*)d_in[0];
    const float* ve    = (const float*)d_in[1];
    const float* cosb  = (const float*)d_in[2];
    const float* sinb  = (const float*)d_in[3];
    const float* Wq    = (const float*)d_in[4];
    const float* Wk    = (const float*)d_in[5];
    const float* Wv    = (const float*)d_in[6];
    const float* Wproj = (const float*)d_in[7];
    const float* Wg    = (const float*)d_in[8];
    const int*   wptr  = (const int*)d_in[9];
    float* out = (float*)d_out;

    // workspace layout (all bf16/ushort), ~63 MB
    ushort* xb    = (ushort*)d_ws;                    // M*C
    ushort* vbuf  = xb    + (size_t)M_ * C_;          // M*512
    ushort* Qp    = vbuf  + (size_t)M_ * 512;         // M*C (permuted d)
    ushort* Kp    = Qp    + (size_t)M_ * C_;          // M*512 (permuted d)
    ushort* Vt    = Kp    + (size_t)M_ * 512;         // M*512
    ushort* yb16  = Vt    + (size_t)M_ * 512;         // M*C
    ushort* Wqkvb = yb16  + (size_t)M_ * C_;          // 2560*C (q/k rows dperm'd)
    ushort* Wpb   = Wqkvb + (size_t)NQKV_ * C_;       // C*C

    // fused cast of x + all weights (one launch; Wq/Wk rows permuted)
    cast_all<<<SEG4 / 256, 256, 0, stream>>>(x, Wq, Wk, Wv, Wproj, xb, Wqkvb, Wpb);

    // fused q|k|v projection + rope/rms epilogue
    gemm_qkv<<<dim3(NQKV_ / 128, M_ / 128), 256, 0, stream>>>(xb, Wqkvb, Qp, Kp, vbuf,
                                                              cosb, sinb);

    // ve-gate + transpose -> Vt
    gate_vt<<<dim3(T_ / 64, KV_, B_), 256, 0, stream>>>(vbuf, x, ve, Wg, Vt);

    // flash attention -> yb16
    attn_mfma<<<dim3(T_ / 64, H_, B_), 256, 0, stream>>>(Qp, Kp, Vt, yb16, wptr);

    // out = y @ Wproj^T (fp32 out)
    gemm_bf16_bt<false><<<dim3(C_ / 128, M_ / 128), 256, 0, stream>>>(yb16, Wpb, out, M_, C_, C_);
}